// Round 2
// baseline (1150.115 us; speedup 1.0000x reference)
//
#include <hip/hip_runtime.h>
#include <hip/hip_bf16.h>

typedef __hip_bfloat16 bf16;
typedef __attribute__((ext_vector_type(8))) short s16x8;
typedef __attribute__((ext_vector_type(4))) short s16x4;
typedef __attribute__((ext_vector_type(4))) float f32x4;

#define TT 64
#define NN_ 1024
#define EE 512

__device__ __forceinline__ float toF(float v) { return v; }
__device__ __forceinline__ float toF(bf16 v) { return __bfloat162float(v); }
__device__ __forceinline__ bf16 f2b(float v) { return __float2bfloat16(v); }

#if __has_builtin(__builtin_amdgcn_exp2f)
#define EXP2F(x) __builtin_amdgcn_exp2f(x)
#else
#define EXP2F(x) exp2f(x)
#endif
#if __has_builtin(__builtin_amdgcn_logf)
#define LOG2F(x) __builtin_amdgcn_logf(x)
#else
#define LOG2F(x) log2f(x)
#endif

enum { EPI_F32 = 0, EPI_SIG_F32 = 1, EPI_SIG_B16 = 2 };
enum { E_LN1 = 0, E_BF16 = 1, E_LN2 = 2, E_SILU = 3, E_OUT = 4, E_TRI = 5, E_BF16T = 6 };

// ---------------- small fp32 tiled GEMM (S0-S2 only; 1024-row problems) -------------
template <bool TRANSB, int EPI>
__global__ __launch_bounds__(256) void gemm_k(
    const float* __restrict__ A, const float* __restrict__ B,
    float* __restrict__ outF, const float* __restrict__ bias,
    const float* __restrict__ sbeta, float alpha,
    int M, int Nn, int K, int lda, int ldb)
{
    __shared__ float As[16][68];
    __shared__ float Bs[16][68];
    const int tid = threadIdx.x;
    const int tx = tid & 15, ty = tid >> 4;
    const int m0 = blockIdx.x * 64, n0 = blockIdx.y * 64;
    float acc[4][4] = {};

    for (int k0 = 0; k0 < K; k0 += 16) {
        {
            int row = tid >> 2, kk0 = (tid & 3) * 4, grow = m0 + row;
#pragma unroll
            for (int j = 0; j < 4; j++) {
                int kk = kk0 + j, gk = k0 + kk;
                As[kk][row] = (grow < M) ? A[(size_t)grow * lda + gk] : 0.f;
            }
        }
        if (!TRANSB) {
            int kk = tid >> 4, c0 = (tid & 15) * 4;
#pragma unroll
            for (int j = 0; j < 4; j++) {
                int col = c0 + j, gn = n0 + col;
                Bs[kk][col] = (gn < Nn) ? B[(size_t)(k0 + kk) * ldb + gn] : 0.f;
            }
        } else {
            int col = tid >> 2, kk0 = (tid & 3) * 4, gn = n0 + col;
#pragma unroll
            for (int j = 0; j < 4; j++) {
                int kk = kk0 + j;
                Bs[kk][col] = (gn < Nn) ? B[(size_t)gn * ldb + (k0 + kk)] : 0.f;
            }
        }
        __syncthreads();
#pragma unroll
        for (int kk = 0; kk < 16; kk++) {
            float a[4], b[4];
#pragma unroll
            for (int i = 0; i < 4; i++) a[i] = As[kk][ty * 4 + i];
#pragma unroll
            for (int j = 0; j < 4; j++) b[j] = Bs[kk][tx * 4 + j];
#pragma unroll
            for (int i = 0; i < 4; i++)
#pragma unroll
                for (int j = 0; j < 4; j++)
                    acc[i][j] = fmaf(a[i], b[j], acc[i][j]);
        }
        __syncthreads();
    }

    float gb = (EPI != EPI_F32 && sbeta) ? sbeta[0] : 0.f;
#pragma unroll
    for (int i = 0; i < 4; i++) {
        int row = m0 + ty * 4 + i;
        if (row >= M) continue;
#pragma unroll
        for (int j = 0; j < 4; j++) {
            int col = n0 + tx * 4 + j;
            if (col >= Nn) continue;
            float v = acc[i][j];
            if (EPI == EPI_F32) {
                if (bias) v += bias[col];
                outF[(size_t)row * Nn + col] = v;
            } else if (EPI == EPI_SIG_F32) {
                v = v * alpha + gb;
                outF[(size_t)row * Nn + col] = 1.f / (1.f + __expf(-v));
            } else {
                v = v * alpha + gb;
                ((bf16*)outF)[(size_t)row * Nn + col] = f2b(1.f / (1.f + __expf(-v)));
            }
        }
    }
}

// ---------------- MFMA bf16 GEMM -----------------------------------------------------
// C[M,Nn] = A[M,K](bf16) @ BT[Nn,K]^T(bf16), fp32 accum, fused epilogues.
// 256 threads = 4 waves. BK=32. BN=256: waves side-by-side; BM=256/BN=64: stacked.
// CAT: A row r = [A1[(r&rowmask),0:256] | A2[r,0:256]], K=512.
template <int BM, int BN, bool CAT, int EPI>
__global__ __launch_bounds__(256) void mfma_k(
    const bf16* __restrict__ A1, const bf16* __restrict__ A2, unsigned rowmask,
    const bf16* __restrict__ BT, const float* __restrict__ bias,
    float* __restrict__ outF,
    bf16* __restrict__ outB, bf16* __restrict__ outB2,
    const float* __restrict__ g1, const float* __restrict__ b1,
    const float* __restrict__ g2, const float* __restrict__ b2,
    const bf16* __restrict__ resid,
    int M, int K)
{
    constexpr bool LN = (EPI == E_LN1 || EPI == E_LN2);
    constexpr int STAGE_B = (BM * 32 + BN * 32) * 2;
    constexpr int SB = LN ? (64 * 260 * 4) : STAGE_B;
    __shared__ __align__(16) char smem[SB];
    short* As = (short*)smem;
    short* Bs = As + BM * 32;
    float* Cs = (float*)smem;   // LN epilogue reuses staging LDS

    const int tid = threadIdx.x;
    const int wid = tid >> 6, lane = tid & 63;
    const int wr = (BN == 256) ? 0 : wid;
    const int wc = (BN == 256) ? wid : 0;
    const int m0 = blockIdx.x * BM, n0 = blockIdx.y * BN;
    const int srow = tid >> 2;
    const int skoff = (tid & 3) * 8;

    f32x4 acc[4][4] = {};

    for (int k0 = 0; k0 < K; k0 += 32) {
#pragma unroll
        for (int c = 0; c < BM / 64; c++) {
            int r = c * 64 + srow;
            int gr = m0 + r;
            const bf16* p;
            if (CAT) {
                int gk = k0 + skoff;
                p = (gk < 256) ? (A1 + (size_t)(gr & rowmask) * 256 + gk)
                               : (A2 + (size_t)gr * 256 + (gk - 256));
            } else {
                p = A1 + (size_t)gr * K + k0 + skoff;
            }
            *(s16x8*)&As[r * 32 + skoff] = *(const s16x8*)p;
        }
#pragma unroll
        for (int c = 0; c < BN / 64; c++) {
            int r = c * 64 + srow;
            *(s16x8*)&Bs[r * 32 + skoff] =
                *(const s16x8*)(BT + (size_t)(n0 + r) * K + k0 + skoff);
        }
        __syncthreads();
        s16x8 af[4], bf[4];
#pragma unroll
        for (int mi = 0; mi < 4; mi++)
            af[mi] = *(s16x8*)&As[(wr * 64 + mi * 16 + (lane & 15)) * 32 + (lane >> 4) * 8];
#pragma unroll
        for (int ni = 0; ni < 4; ni++)
            bf[ni] = *(s16x8*)&Bs[(wc * 64 + ni * 16 + (lane & 15)) * 32 + (lane >> 4) * 8];
#pragma unroll
        for (int mi = 0; mi < 4; mi++)
#pragma unroll
            for (int ni = 0; ni < 4; ni++)
                acc[mi][ni] = __builtin_amdgcn_mfma_f32_16x16x32_bf16(
                    af[mi], bf[ni], acc[mi][ni], 0, 0, 0);
        __syncthreads();
    }

    if (EPI == E_SILU) {
#pragma unroll
        for (int mi = 0; mi < 4; mi++)
#pragma unroll
            for (int ni = 0; ni < 4; ni++)
#pragma unroll
                for (int r = 0; r < 4; r++) {
                    int row = m0 + wr * 64 + mi * 16 + (lane >> 4) * 4 + r;
                    int col = n0 + wc * 64 + ni * 16 + (lane & 15);
                    float v = acc[mi][ni][r] + bias[col];
                    float s = v / (1.f + __expf(-v));
                    if (col < EE) outB[(size_t)row * EE + col] = f2b(s);
                    else          outB2[(size_t)row * EE + (col - EE)] = f2b(s);
                }
    } else if (EPI == E_BF16) {
#pragma unroll
        for (int mi = 0; mi < 4; mi++)
#pragma unroll
            for (int ni = 0; ni < 4; ni++)
#pragma unroll
                for (int r = 0; r < 4; r++) {
                    int row = m0 + wr * 64 + mi * 16 + (lane >> 4) * 4 + r;
                    int col = n0 + wc * 64 + ni * 16 + (lane & 15);
                    outB[(size_t)row * 256 + col] = f2b(acc[mi][ni][r] + bias[col]);
                }
    } else if (EPI == E_BF16T) {
        // rows r = t*1024+j -> store transposed [t][col][j]
#pragma unroll
        for (int mi = 0; mi < 4; mi++)
#pragma unroll
            for (int ni = 0; ni < 4; ni++)
#pragma unroll
                for (int r = 0; r < 4; r++) {
                    int row = m0 + wr * 64 + mi * 16 + (lane >> 4) * 4 + r;
                    int col = n0 + wc * 64 + ni * 16 + (lane & 15);
                    size_t dst = (((size_t)(row >> 10)) * 256 + col) * 1024 + (row & 1023);
                    outB[dst] = f2b(acc[mi][ni][r] + bias[col]);
                }
    } else if (EPI == E_OUT) {
#pragma unroll
        for (int mi = 0; mi < 4; mi++)
#pragma unroll
            for (int ni = 0; ni < 4; ni++)
#pragma unroll
                for (int r = 0; r < 4; r++) {
                    int row = m0 + wr * 64 + mi * 16 + (lane >> 4) * 4 + r;
                    int col = n0 + wc * 64 + ni * 16 + (lane & 15);
                    float v = acc[mi][ni][r] + bias[col] + toF(resid[(size_t)row * 256 + col]);
                    int t = row & 63, n = row >> 6;
                    outF[((size_t)t * NN_ + n) * 256 + col] = v;
                }
    } else if (EPI == E_TRI) {
        // dbc[M,48]: cols 0-15 d1, 16-31 Bm, 32-47 Cm
#pragma unroll
        for (int mi = 0; mi < 4; mi++)
#pragma unroll
            for (int ni = 0; ni < 4; ni++)
#pragma unroll
                for (int r = 0; r < 4; r++) {
                    int row = m0 + wid * 64 + mi * 16 + (lane >> 4) * 4 + r;
                    int col = ni * 16 + (lane & 15);
                    if (col < 48) {
                        float v = acc[mi][ni][r] + bias[col];
                        outF[(size_t)row * 48 + col] = v;
                    }
                }
    } else {
        // E_LN1 / E_LN2: relu -> Cs, then row LN(s). BM=64, BN=256, grid.y=1.
#pragma unroll
        for (int mi = 0; mi < 4; mi++)
#pragma unroll
            for (int ni = 0; ni < 4; ni++)
#pragma unroll
                for (int r = 0; r < 4; r++) {
                    int rl = mi * 16 + (lane >> 4) * 4 + r;
                    int cl = wc * 64 + ni * 16 + (lane & 15);
                    Cs[rl * 260 + cl] = fmaxf(acc[mi][ni][r] + bias[cl], 0.f);
                }
        __syncthreads();
        float g1v[4], b1v[4], g2v[4], b2v[4];
#pragma unroll
        for (int i = 0; i < 4; i++) {
            g1v[i] = g1[lane * 4 + i];
            b1v[i] = b1[lane * 4 + i];
            if (EPI == E_LN2) { g2v[i] = g2[lane * 4 + i]; b2v[i] = b2[lane * 4 + i]; }
        }
        for (int rr = 0; rr < 16; rr++) {
            int rl = wid * 16 + rr;
            int grow = m0 + rl;
            float x[4];
#pragma unroll
            for (int i = 0; i < 4; i++) x[i] = Cs[rl * 260 + lane * 4 + i];
            float s = x[0] + x[1] + x[2] + x[3];
#pragma unroll
            for (int o = 1; o < 64; o <<= 1) s += __shfl_xor(s, o, 64);
            float mu = s * (1.f / 256.f);
            float d[4], ss = 0.f;
#pragma unroll
            for (int i = 0; i < 4; i++) { d[i] = x[i] - mu; ss = fmaf(d[i], d[i], ss); }
#pragma unroll
            for (int o = 1; o < 64; o <<= 1) ss += __shfl_xor(ss, o, 64);
            float inv = rsqrtf(fmaxf(ss * (1.f / 256.f), 0.f) + 1e-5f);
            float y[4];
#pragma unroll
            for (int i = 0; i < 4; i++) y[i] = d[i] * inv * g1v[i] + b1v[i];
            if (EPI == E_LN1) {
                __align__(8) bf16 pk[4];
#pragma unroll
                for (int i = 0; i < 4; i++) pk[i] = f2b(y[i]);
                *(s16x4*)&outB[(size_t)grow * 256 + lane * 4] = *(s16x4*)pk;
            } else {
                int trow = (grow & 1023) * 64 + (grow >> 10);   // [N,T] order
                __align__(8) bf16 pk[4];
#pragma unroll
                for (int i = 0; i < 4; i++) pk[i] = f2b(y[i]);
                *(s16x4*)&outB[(size_t)trow * 256 + lane * 4] = *(s16x4*)pk;
                float s2 = y[0] + y[1] + y[2] + y[3];
#pragma unroll
                for (int o = 1; o < 64; o <<= 1) s2 += __shfl_xor(s2, o, 64);
                float mu2 = s2 * (1.f / 256.f);
                float d2[4], ss2 = 0.f;
#pragma unroll
                for (int i = 0; i < 4; i++) { d2[i] = y[i] - mu2; ss2 = fmaf(d2[i], d2[i], ss2); }
#pragma unroll
                for (int o = 1; o < 64; o <<= 1) ss2 += __shfl_xor(ss2, o, 64);
                float inv2 = rsqrtf(fmaxf(ss2 * (1.f / 256.f), 0.f) + 1e-5f);
                __align__(8) bf16 pk2[4];
#pragma unroll
                for (int i = 0; i < 4; i++) pk2[i] = f2b(d2[i] * inv2 * g2v[i] + b2v[i]);
                *(s16x4*)&outB2[(size_t)trow * 256 + lane * 4] = *(s16x4*)pk2;
            }
        }
    }
}

// ---------------- adj bit-pack: adj in {0,1} -> 1 bit/elem (268MB -> 8.4MB) --------
__global__ __launch_bounds__(256) void packadj_k(
    const float* __restrict__ adj, unsigned long long* __restrict__ bits)
{
    const int gw = (blockIdx.x * 256 + threadIdx.x) >> 6;   // global wave id (0..4095)
    const int lane = threadIdx.x & 63;
    const size_t total = (size_t)TT * NN_ * NN_;
    for (size_t base = (size_t)gw * 64; base < total; base += (size_t)4096 * 64) {
        float v = adj[base + lane];
        unsigned long long m = __ballot(v != 0.f);
        if (lane == 0) bits[base >> 6] = m;
    }
}

// ---------------- dense MFMA aggregation via bitmask -------------------------------
// adj in {0,1}: A-tile element = bit ? (GATED ? gate_bf16 : 1.0bf) : 0 -- bit-exact
// with f2b(adj*gate). Per K-step staging: 1 byte (adj bits) + s16x8 gates + s16x8 B.
// All staged data is L2/L3-resident (bits 8.4MB, gates 2MB, msgsT 512KB/t).
// BM=128 x BN=256, 4 waves (wave tile 64x128), 1-deep register prefetch.
template <bool GATED>
__global__ __launch_bounds__(256, 2) void aggmm_k(
    const unsigned char* __restrict__ adjbits, const bf16* __restrict__ gatesb,
    const bf16* __restrict__ BTsrc, bf16* __restrict__ out)
{
    __shared__ __align__(16) short As[128 * 40];
    __shared__ __align__(16) short Bs[256 * 40];
    const int tid = threadIdx.x;
    const int wid = tid >> 6, lane = tid & 63;
    const int wr = wid & 1;          // wave rows: wr*64
    const int wc = wid >> 1;         // wave cols: wc*128
    const int bx = blockIdx.x;
    const int t = bx >> 3, n0 = (bx & 7) * 128;
    const int srow = tid >> 2;       // 0..63
    const int skoff = (tid & 3) * 8; // 0,8,16,24

    // byte covering k-range [k0+skoff, k0+skoff+8) of row r: r*128 + k0/8 + (tid&3)
    const unsigned char* __restrict__ abB =
        adjbits + ((size_t)t * 1024 + n0) * 128 + (tid & 3);
    const bf16* __restrict__ gB = GATED ? (gatesb + (size_t)n0 * 1024 + skoff) : nullptr;
    const bf16* __restrict__ bt = GATED ? BTsrc : (BTsrc + (size_t)t * 256 * 1024);
    const size_t orow0 = (size_t)t * 1024 + n0;

    f32x4 acc[4][8] = {};

    unsigned char pm[2];
    s16x8 pg[2];
    s16x8 pb[4];

    auto LOADA = [&](int k0) {
#pragma unroll
        for (int c = 0; c < 2; c++) {
            int r = c * 64 + srow;
            pm[c] = abB[(size_t)r * 128 + (k0 >> 3)];
            if (GATED) pg[c] = *(const s16x8*)(gB + (size_t)r * 1024 + k0);
        }
#pragma unroll
        for (int c = 0; c < 4; c++)
            pb[c] = *(const s16x8*)(bt + (size_t)(c * 64 + srow) * 1024 + k0 + skoff);
    };
    auto STORE = [&]() {
#pragma unroll
        for (int c = 0; c < 2; c++) {
            unsigned m = pm[c];
            s16x8 tmp;
            if (GATED) {
#pragma unroll
                for (int i = 0; i < 8; i++) tmp[i] = ((m >> i) & 1) ? pg[c][i] : (short)0;
            } else {
#pragma unroll
                for (int i = 0; i < 8; i++) tmp[i] = ((m >> i) & 1) ? (short)0x3F80 : (short)0;
            }
            *(s16x8*)&As[(c * 64 + srow) * 40 + skoff] = tmp;
        }
#pragma unroll
        for (int c = 0; c < 4; c++)
            *(s16x8*)&Bs[(c * 64 + srow) * 40 + skoff] = pb[c];
    };

    LOADA(0);
#pragma unroll 1
    for (int k0 = 0; k0 < 1024; k0 += 32) {
        STORE();
        __syncthreads();
        if (k0 + 32 < 1024) LOADA(k0 + 32);   // next tile in flight during MFMA
        s16x8 af[4];
#pragma unroll
        for (int mi = 0; mi < 4; mi++)
            af[mi] = *(s16x8*)&As[(wr * 64 + mi * 16 + (lane & 15)) * 40 + (lane >> 4) * 8];
#pragma unroll
        for (int ni = 0; ni < 8; ni++) {
            s16x8 bfv = *(s16x8*)&Bs[(wc * 128 + ni * 16 + (lane & 15)) * 40 + (lane >> 4) * 8];
#pragma unroll
            for (int mi = 0; mi < 4; mi++)
                acc[mi][ni] = __builtin_amdgcn_mfma_f32_16x16x32_bf16(
                    af[mi], bfv, acc[mi][ni], 0, 0, 0);
        }
        __syncthreads();
    }

#pragma unroll
    for (int mi = 0; mi < 4; mi++)
#pragma unroll
        for (int ni = 0; ni < 8; ni++)
#pragma unroll
            for (int r = 0; r < 4; r++) {
                int rowl = wr * 64 + mi * 16 + (lane >> 4) * 4 + r;
                int col = wc * 128 + ni * 16 + (lane & 15);
                out[(orow0 + rowl) * 256 + col] = f2b(acc[mi][ni][r]);
            }
}

// ---------------- Mamba selective scan (block = n, thread = e) ----------------------
// dbc[M,48] rows: [d1(16) | Bm(16) | Cm(16)]. n = blockIdx -> dbc reads are
// wave-uniform (s_load). al[] pre-folds log2e so the hot loop is mul+v_exp per s.
// 4-way trees break the serial fma chains; unroll 2 overlaps t+1 proj with t update.
__global__ __launch_bounds__(512) void scan_k(
    const bf16* __restrict__ u, const bf16* __restrict__ sg,
    const float* __restrict__ dbc,
    const float* __restrict__ Wdt, const float* __restrict__ bdt,
    const float* __restrict__ Alog, const float* __restrict__ D,
    bf16* __restrict__ yg)
{
    const int n = blockIdx.x, e = threadIdx.x;
    float al[16], wdt[16], h[16];
#pragma unroll
    for (int s = 0; s < 16; s++) {
        al[s] = -__expf(Alog[e * 16 + s]) * 1.44269504f;   // * log2(e)
        h[s] = 0.f;
    }
#pragma unroll
    for (int k = 0; k < 16; k++) wdt[k] = Wdt[(size_t)k * EE + e];
    const float bdte = bdt[e], De = D[e];
    const float* __restrict__ rowp = dbc + (size_t)n * TT * 48;
    const size_t base = (size_t)n * TT * EE + e;
#pragma unroll 2
    for (int t = 0; t < TT; t++) {
        const float* __restrict__ r = rowp + t * 48;
        float a0 = bdte, a1 = 0.f, a2 = 0.f, a3 = 0.f;
#pragma unroll
        for (int k = 0; k < 4; k++) {
            a0 = fmaf(r[k],      wdt[k],      a0);
            a1 = fmaf(r[k + 4],  wdt[k + 4],  a1);
            a2 = fmaf(r[k + 8],  wdt[k + 8],  a2);
            a3 = fmaf(r[k + 12], wdt[k + 12], a3);
        }
        float acc = (a0 + a1) + (a2 + a3);
        float delta = (acc > 20.f)
            ? acc
            : 0.69314718056f * LOG2F(1.f + EXP2F(acc * 1.44269504f));
        size_t idx = base + (size_t)t * EE;
        float uv = toF(u[idx]);
        float du = delta * uv;
        float y0 = 0.f, y1 = 0.f, y2 = 0.f, y3 = 0.f;
#pragma unroll
        for (int s = 0; s < 16; s += 4) {
            float ad0 = EXP2F(delta * al[s]);
            float ad1 = EXP2F(delta * al[s + 1]);
            float ad2 = EXP2F(delta * al[s + 2]);
            float ad3 = EXP2F(delta * al[s + 3]);
            h[s]     = fmaf(ad0, h[s],     du * r[16 + s]);
            h[s + 1] = fmaf(ad1, h[s + 1], du * r[17 + s]);
            h[s + 2] = fmaf(ad2, h[s + 2], du * r[18 + s]);
            h[s + 3] = fmaf(ad3, h[s + 3], du * r[19 + s]);
            y0 = fmaf(r[32 + s], h[s],     y0);
            y1 = fmaf(r[33 + s], h[s + 1], y1);
            y2 = fmaf(r[34 + s], h[s + 2], y2);
            y3 = fmaf(r[35 + s], h[s + 3], y3);
        }
        float y = (y0 + y1) + (y2 + y3);
        yg[idx] = f2b((y + uv * De) * toF(sg[idx]));
    }
}

// ---------------- prep kernels ------------------------------------------------------
__global__ void cast_k(const float* __restrict__ in, bf16* __restrict__ out, int n) {
    int i = blockIdx.x * 256 + threadIdx.x;
    if (i < n) out[i] = f2b(in[i]);
}
__global__ void transT_k(const float* __restrict__ W, bf16* __restrict__ out, int K, int Nn) {
    int gid = blockIdx.x * 256 + threadIdx.x;
    if (gid >= K * Nn) return;
    int n = gid / K, k = gid - n * K;
    out[gid] = f2b(W[(size_t)k * Nn + n]);
}
__global__ void transmsgs_k(const float* __restrict__ msgs, bf16* __restrict__ msgsT) {
    int gid = blockIdx.x * 256 + threadIdx.x;
    int c = gid >> 10, j = gid & 1023;
    msgsT[gid] = f2b(msgs[(size_t)j * 256 + c]);
}
__global__ void wdbct_k(const float* __restrict__ Wd, const float* __restrict__ WB,
                        const float* __restrict__ WC, bf16* __restrict__ out,
                        const float* __restrict__ bd, const float* __restrict__ bB,
                        const float* __restrict__ bC, float* __restrict__ biascat) {
    int gid = blockIdx.x * 256 + threadIdx.x;
    if (gid < 48) biascat[gid] = (gid < 16) ? bd[gid] : (gid < 32) ? bB[gid - 16] : bC[gid - 32];
    if (gid >= 64 * 512) return;
    int n = gid >> 9, k = gid & 511;
    float v = 0.f;
    if (n < 16)      v = Wd[(size_t)k * 16 + n];
    else if (n < 32) v = WB[(size_t)k * 16 + (n - 16)];
    else if (n < 48) v = WC[(size_t)k * 16 + (n - 32)];
    out[gid] = f2b(v);
}

extern "C" void kernel_launch(void* const* d_in, const int* in_sizes, int n_in,
                              void* d_out, int out_size, void* d_ws, size_t ws_size,
                              hipStream_t stream)
{
    const float* adj   = (const float*)d_in[0];
    const float* pos   = (const float*)d_in[1];
    const float* g1Wm  = (const float*)d_in[2];
    const float* g1bm  = (const float*)d_in[3];
    const float* g1Wq  = (const float*)d_in[4];
    const float* g1Wk  = (const float*)d_in[5];
    const float* g1gb  = (const float*)d_in[6];
    const float* g1Wu  = (const float*)d_in[7];
    const float* g1bu  = (const float*)d_in[8];
    const float* g1lg  = (const float*)d_in[9];
    const float* g1lb  = (const float*)d_in[10];
    const float* g2Wm  = (const float*)d_in[11];
    const float* g2bm  = (const float*)d_in[12];
    const float* g2Wu  = (const float*)d_in[13];
    const float* g2bu  = (const float*)d_in[14];
    const float* g2lg  = (const float*)d_in[15];
    const float* g2lb  = (const float*)d_in[16];
    const float* mlg   = (const float*)d_in[17];
    const float* mlb   = (const float*)d_in[18];
    const float* mWin  = (const float*)d_in[19];
    const float* mbin  = (const float*)d_in[20];
    const float* mWd   = (const float*)d_in[21];
    const float* mbd   = (const float*)d_in[22];
    const float* mWdt  = (const float*)d_in[23];
    const float* mbdt  = (const float*)d_in[24];
    const float* mWB   = (const float*)d_in[25];
    const float* mbB   = (const float*)d_in[26];
    const float* mWC   = (const float*)d_in[27];
    const float* mbC   = (const float*)d_in[28];
    const float* mAlog = (const float*)d_in[29];
    const float* mD    = (const float*)d_in[30];
    const float* mWout = (const float*)d_in[31];
    const float* mbout = (const float*)d_in[32];
    float* out = (float*)d_out;
    char* ws = (char*)d_ws;

    const size_t BIGE = (size_t)TT * NN_ * 256;
    size_t o = 0;
    auto alloc = [&](size_t bytes) { size_t r = o; o += (bytes + 255) & ~(size_t)255; return r; };

    float* msgs  = (float*)(ws + alloc((size_t)NN_ * 256 * 4));
    float* q     = (float*)(ws + alloc((size_t)NN_ * 256 * 4));
    float* kk    = (float*)(ws + alloc((size_t)NN_ * 256 * 4));
    bf16*  gatesb = (bf16*)(ws + alloc((size_t)NN_ * NN_ * 2));
    unsigned long long* adjbits =
        (unsigned long long*)(ws + alloc((size_t)TT * NN_ * NN_ / 8));
    bf16*  Ra    = (bf16*)(ws + alloc(BIGE * 2));                 // agg / xn
    size_t off_x1 = alloc(BIGE * 2);
    bf16*  x1    = (bf16*)(ws + off_x1);
    bf16*  agg2  = (bf16*)(ws + alloc(BIGE * 2));                 // contiguous after x1
    bf16*  x2    = (bf16*)(ws + alloc(BIGE * 2));                 // res, [N,T,H]
    bf16*  yg    = (bf16*)(ws + alloc(BIGE * 2));
    bf16*  sg    = (bf16*)(ws + alloc((size_t)NN_ * TT * EE * 2));
    float* dbc   = (float*)(ws + alloc((size_t)TT * NN_ * 48 * 4));  // [M,48] d1|Bm|Cm
    bf16*  u     = (bf16*)(ws + off_x1);                          // aliases x1+agg2
    // transposed bf16 weights / staging
    bf16* posb   = (bf16*)(ws + alloc((size_t)NN_ * 256 * 2));
    bf16* g1WuT  = (bf16*)(ws + alloc((size_t)256 * 512 * 2));
    bf16* g2WmT  = (bf16*)(ws + alloc((size_t)256 * 256 * 2));
    bf16* g2WuT  = (bf16*)(ws + alloc((size_t)256 * 512 * 2));
    bf16* mWinT  = (bf16*)(ws + alloc((size_t)1024 * 256 * 2));
    bf16* mWoutT = (bf16*)(ws + alloc((size_t)256 * 512 * 2));
    bf16* WdBCT  = (bf16*)(ws + alloc((size_t)64 * 512 * 2));
    float* biascat = (float*)(ws + alloc(64 * 4));
    bf16* msgsT  = (bf16*)(ws + alloc((size_t)256 * 1024 * 2));
    bf16* msgs2T = (bf16*)(ws + alloc(BIGE * 2));

    const unsigned ALLR = 0xFFFFFFFFu;
    const int M = TT * NN_;

    // prep
    packadj_k<<<1024, 256, 0, stream>>>(adj, adjbits);
    cast_k<<<NN_, 256, 0, stream>>>(pos, posb, NN_ * 256);
    transT_k<<<(512 * 256 + 255) / 256, 256, 0, stream>>>(g1Wu, g1WuT, 512, 256);
    transT_k<<<(256 * 256 + 255) / 256, 256, 0, stream>>>(g2Wm, g2WmT, 256, 256);
    transT_k<<<(512 * 256 + 255) / 256, 256, 0, stream>>>(g2Wu, g2WuT, 512, 256);
    transT_k<<<(256 * 1024 + 255) / 256, 256, 0, stream>>>(mWin, mWinT, 256, 1024);
    transT_k<<<(512 * 256 + 255) / 256, 256, 0, stream>>>(mWout, mWoutT, 512, 256);
    wdbct_k<<<(64 * 512 + 255) / 256, 256, 0, stream>>>(mWd, mWB, mWC, WdBCT, mbd, mbB, mbC, biascat);

    // S0: msgs = pos @ g1_Wm + bm (f32)
    gemm_k<false, EPI_F32><<<dim3(16, 4), 256, 0, stream>>>(
        pos, g1Wm, msgs, g1bm, nullptr, 1.f, NN_, 256, 256, 256, 256);
    transmsgs_k<<<1024, 256, 0, stream>>>(msgs, msgsT);
    // S1: q, k
    gemm_k<false, EPI_F32><<<dim3(16, 4), 256, 0, stream>>>(
        msgs, g1Wq, q, nullptr, nullptr, 1.f, NN_, 256, 256, 256, 256);
    gemm_k<false, EPI_F32><<<dim3(16, 4), 256, 0, stream>>>(
        msgs, g1Wk, kk, nullptr, nullptr, 1.f, NN_, 256, 256, 256, 256);
    // S2: gates = sigmoid(q @ k^T / 16 + gb) -> bf16 (exact wrt old f2b(adj*gate))
    gemm_k<true, EPI_SIG_B16><<<dim3(16, 16), 256, 0, stream>>>(
        q, kk, (float*)gatesb, nullptr, g1gb, 1.f / 16.f, NN_, NN_, 256, 256, 256);
    // S3: agg -> Ra
    aggmm_k<true><<<512, 256, 0, stream>>>(
        (const unsigned char*)adjbits, gatesb, msgsT, Ra);
    // S4(+S5): x1 = LN(relu(cat(posb,Ra) @ Wu1 + bu1))
    mfma_k<64, 256, true, E_LN1><<<dim3(1024, 1), 256, 0, stream>>>(
        posb, Ra, 1023u, g1WuT, g1bu, nullptr, x1, nullptr,
        g1lg, g1lb, nullptr, nullptr, nullptr, M, 512);
    // S6: msgs2 = x1 @ Wm2 + bm2 -> msgs2T ([t][c][j])
    mfma_k<64, 256, false, E_BF16T><<<dim3(1024, 1), 256, 0, stream>>>(
        x1, x1, ALLR, g2WmT, g2bm, nullptr, msgs2T, nullptr,
        nullptr, nullptr, nullptr, nullptr, nullptr, M, 256);
    // S7: agg2 = adj @ msgs2
    aggmm_k<false><<<512, 256, 0, stream>>>(
        (const unsigned char*)adjbits, nullptr, msgs2T, agg2);
    // S8(+S9+S10): x2 = LN(relu(cat(x1,agg2)@Wu2+bu2)) [N,T,H], xn = LN2 -> Ra [N,T,H]
    mfma_k<64, 256, true, E_LN2><<<dim3(1024, 1), 256, 0, stream>>>(
        x1, agg2, ALLR, g2WuT, g2bu, nullptr, x2, Ra,
        g2lg, g2lb, mlg, mlb, nullptr, M, 512);
    // S11: u/sg = silu halves of xn @ Win + bin
    mfma_k<64, 256, false, E_SILU><<<dim3(1024, 4), 256, 0, stream>>>(
        Ra, Ra, ALLR, mWinT, mbin, nullptr, u, sg,
        nullptr, nullptr, nullptr, nullptr, nullptr, M, 256);
    // S12 fused: dbc = u @ [Wd|WB|WC] + biases  ([M,48] interleaved)
    mfma_k<256, 64, false, E_TRI><<<dim3(256, 1), 256, 0, stream>>>(
        u, u, ALLR, WdBCT, biascat, dbc, nullptr, nullptr,
        nullptr, nullptr, nullptr, nullptr, nullptr, M, 512);
    // S13: selective scan -> yg  (block per n, thread per e)
    scan_k<<<NN_, 512, 0, stream>>>(u, sg, dbc, mWdt, mbdt, mAlog, mD, yg);
    // S14: out = yg @ Wout + bout + res -> [T,N,H] f32
    mfma_k<64, 256, false, E_OUT><<<dim3(1024, 1), 256, 0, stream>>>(
        yg, yg, ALLR, mWoutT, mbout, out, nullptr, nullptr,
        nullptr, nullptr, nullptr, nullptr, x2, M, 512);

    (void)in_sizes; (void)n_in; (void)out_size; (void)ws_size;
}

// Round 3
// 1075.134 us; speedup vs baseline: 1.0697x; 1.0697x over previous
//
#include <hip/hip_runtime.h>
#include <hip/hip_bf16.h>

typedef __hip_bfloat16 bf16;
typedef __attribute__((ext_vector_type(8))) short s16x8;
typedef __attribute__((ext_vector_type(4))) short s16x4;
typedef __attribute__((ext_vector_type(4))) float f32x4;

#define TT 64
#define NN_ 1024
#define EE 512

__device__ __forceinline__ float toF(float v) { return v; }
__device__ __forceinline__ float toF(bf16 v) { return __bfloat162float(v); }
__device__ __forceinline__ bf16 f2b(float v) { return __float2bfloat16(v); }

#if __has_builtin(__builtin_amdgcn_exp2f)
#define EXP2F(x) __builtin_amdgcn_exp2f(x)
#else
#define EXP2F(x) exp2f(x)
#endif
#if __has_builtin(__builtin_amdgcn_logf)
#define LOG2F(x) __builtin_amdgcn_logf(x)
#else
#define LOG2F(x) log2f(x)
#endif

enum { EPI_F32 = 0, EPI_SIG_F32 = 1, EPI_SIG_B16 = 2 };
enum { E_LN1 = 0, E_BF16 = 1, E_LN2 = 2, E_SILU = 3, E_OUT = 4, E_TRI = 5, E_BF16T = 6 };

// ---------------- small fp32 tiled GEMM (S0-S2 only; 1024-row problems) -------------
template <bool TRANSB, int EPI>
__global__ __launch_bounds__(256) void gemm_k(
    const float* __restrict__ A, const float* __restrict__ B,
    float* __restrict__ outF, const float* __restrict__ bias,
    const float* __restrict__ sbeta, float alpha,
    int M, int Nn, int K, int lda, int ldb)
{
    __shared__ float As[16][68];
    __shared__ float Bs[16][68];
    const int tid = threadIdx.x;
    const int tx = tid & 15, ty = tid >> 4;
    const int m0 = blockIdx.x * 64, n0 = blockIdx.y * 64;
    float acc[4][4] = {};

    for (int k0 = 0; k0 < K; k0 += 16) {
        {
            int row = tid >> 2, kk0 = (tid & 3) * 4, grow = m0 + row;
#pragma unroll
            for (int j = 0; j < 4; j++) {
                int kk = kk0 + j, gk = k0 + kk;
                As[kk][row] = (grow < M) ? A[(size_t)grow * lda + gk] : 0.f;
            }
        }
        if (!TRANSB) {
            int kk = tid >> 4, c0 = (tid & 15) * 4;
#pragma unroll
            for (int j = 0; j < 4; j++) {
                int col = c0 + j, gn = n0 + col;
                Bs[kk][col] = (gn < Nn) ? B[(size_t)(k0 + kk) * ldb + gn] : 0.f;
            }
        } else {
            int col = tid >> 2, kk0 = (tid & 3) * 4, gn = n0 + col;
#pragma unroll
            for (int j = 0; j < 4; j++) {
                int kk = kk0 + j;
                Bs[kk][col] = (gn < Nn) ? B[(size_t)gn * ldb + (k0 + kk)] : 0.f;
            }
        }
        __syncthreads();
#pragma unroll
        for (int kk = 0; kk < 16; kk++) {
            float a[4], b[4];
#pragma unroll
            for (int i = 0; i < 4; i++) a[i] = As[kk][ty * 4 + i];
#pragma unroll
            for (int j = 0; j < 4; j++) b[j] = Bs[kk][tx * 4 + j];
#pragma unroll
            for (int i = 0; i < 4; i++)
#pragma unroll
                for (int j = 0; j < 4; j++)
                    acc[i][j] = fmaf(a[i], b[j], acc[i][j]);
        }
        __syncthreads();
    }

    float gb = (EPI != EPI_F32 && sbeta) ? sbeta[0] : 0.f;
#pragma unroll
    for (int i = 0; i < 4; i++) {
        int row = m0 + ty * 4 + i;
        if (row >= M) continue;
#pragma unroll
        for (int j = 0; j < 4; j++) {
            int col = n0 + tx * 4 + j;
            if (col >= Nn) continue;
            float v = acc[i][j];
            if (EPI == EPI_F32) {
                if (bias) v += bias[col];
                outF[(size_t)row * Nn + col] = v;
            } else if (EPI == EPI_SIG_F32) {
                v = v * alpha + gb;
                outF[(size_t)row * Nn + col] = 1.f / (1.f + __expf(-v));
            } else {
                v = v * alpha + gb;
                ((bf16*)outF)[(size_t)row * Nn + col] = f2b(1.f / (1.f + __expf(-v)));
            }
        }
    }
}

// ---------------- MFMA bf16 GEMM -----------------------------------------------------
// C[M,Nn] = A[M,K](bf16) @ BT[Nn,K]^T(bf16), fp32 accum, fused epilogues.
// 256 threads = 4 waves. BK=32. BN=256: waves side-by-side; BM=256/BN=64: stacked.
// CAT: A row r = [A1[(r&rowmask),0:256] | A2[r,0:256]], K=512.
template <int BM, int BN, bool CAT, int EPI>
__global__ __launch_bounds__(256) void mfma_k(
    const bf16* __restrict__ A1, const bf16* __restrict__ A2, unsigned rowmask,
    const bf16* __restrict__ BT, const float* __restrict__ bias,
    float* __restrict__ outF,
    bf16* __restrict__ outB, bf16* __restrict__ outB2,
    const float* __restrict__ g1, const float* __restrict__ b1,
    const float* __restrict__ g2, const float* __restrict__ b2,
    const bf16* __restrict__ resid,
    int M, int K)
{
    constexpr bool LN = (EPI == E_LN1 || EPI == E_LN2);
    constexpr int STAGE_B = (BM * 32 + BN * 32) * 2;
    constexpr int SB = LN ? (64 * 260 * 4) : STAGE_B;
    __shared__ __align__(16) char smem[SB];
    short* As = (short*)smem;
    short* Bs = As + BM * 32;
    float* Cs = (float*)smem;   // LN epilogue reuses staging LDS

    const int tid = threadIdx.x;
    const int wid = tid >> 6, lane = tid & 63;
    const int wr = (BN == 256) ? 0 : wid;
    const int wc = (BN == 256) ? wid : 0;
    const int m0 = blockIdx.x * BM, n0 = blockIdx.y * BN;
    const int srow = tid >> 2;
    const int skoff = (tid & 3) * 8;

    f32x4 acc[4][4] = {};

    for (int k0 = 0; k0 < K; k0 += 32) {
#pragma unroll
        for (int c = 0; c < BM / 64; c++) {
            int r = c * 64 + srow;
            int gr = m0 + r;
            const bf16* p;
            if (CAT) {
                int gk = k0 + skoff;
                p = (gk < 256) ? (A1 + (size_t)(gr & rowmask) * 256 + gk)
                               : (A2 + (size_t)gr * 256 + (gk - 256));
            } else {
                p = A1 + (size_t)gr * K + k0 + skoff;
            }
            *(s16x8*)&As[r * 32 + skoff] = *(const s16x8*)p;
        }
#pragma unroll
        for (int c = 0; c < BN / 64; c++) {
            int r = c * 64 + srow;
            *(s16x8*)&Bs[r * 32 + skoff] =
                *(const s16x8*)(BT + (size_t)(n0 + r) * K + k0 + skoff);
        }
        __syncthreads();
        s16x8 af[4], bf[4];
#pragma unroll
        for (int mi = 0; mi < 4; mi++)
            af[mi] = *(s16x8*)&As[(wr * 64 + mi * 16 + (lane & 15)) * 32 + (lane >> 4) * 8];
#pragma unroll
        for (int ni = 0; ni < 4; ni++)
            bf[ni] = *(s16x8*)&Bs[(wc * 64 + ni * 16 + (lane & 15)) * 32 + (lane >> 4) * 8];
#pragma unroll
        for (int mi = 0; mi < 4; mi++)
#pragma unroll
            for (int ni = 0; ni < 4; ni++)
                acc[mi][ni] = __builtin_amdgcn_mfma_f32_16x16x32_bf16(
                    af[mi], bf[ni], acc[mi][ni], 0, 0, 0);
        __syncthreads();
    }

    if (EPI == E_SILU) {
#pragma unroll
        for (int mi = 0; mi < 4; mi++)
#pragma unroll
            for (int ni = 0; ni < 4; ni++)
#pragma unroll
                for (int r = 0; r < 4; r++) {
                    int row = m0 + wr * 64 + mi * 16 + (lane >> 4) * 4 + r;
                    int col = n0 + wc * 64 + ni * 16 + (lane & 15);
                    float v = acc[mi][ni][r] + bias[col];
                    float s = v / (1.f + __expf(-v));
                    if (col < EE) outB[(size_t)row * EE + col] = f2b(s);
                    else          outB2[(size_t)row * EE + (col - EE)] = f2b(s);
                }
    } else if (EPI == E_BF16) {
#pragma unroll
        for (int mi = 0; mi < 4; mi++)
#pragma unroll
            for (int ni = 0; ni < 4; ni++)
#pragma unroll
                for (int r = 0; r < 4; r++) {
                    int row = m0 + wr * 64 + mi * 16 + (lane >> 4) * 4 + r;
                    int col = n0 + wc * 64 + ni * 16 + (lane & 15);
                    outB[(size_t)row * 256 + col] = f2b(acc[mi][ni][r] + bias[col]);
                }
    } else if (EPI == E_BF16T) {
        // rows r = t*1024+j -> store transposed [t][col][j]
#pragma unroll
        for (int mi = 0; mi < 4; mi++)
#pragma unroll
            for (int ni = 0; ni < 4; ni++)
#pragma unroll
                for (int r = 0; r < 4; r++) {
                    int row = m0 + wr * 64 + mi * 16 + (lane >> 4) * 4 + r;
                    int col = n0 + wc * 64 + ni * 16 + (lane & 15);
                    size_t dst = (((size_t)(row >> 10)) * 256 + col) * 1024 + (row & 1023);
                    outB[dst] = f2b(acc[mi][ni][r] + bias[col]);
                }
    } else if (EPI == E_OUT) {
#pragma unroll
        for (int mi = 0; mi < 4; mi++)
#pragma unroll
            for (int ni = 0; ni < 4; ni++)
#pragma unroll
                for (int r = 0; r < 4; r++) {
                    int row = m0 + wr * 64 + mi * 16 + (lane >> 4) * 4 + r;
                    int col = n0 + wc * 64 + ni * 16 + (lane & 15);
                    float v = acc[mi][ni][r] + bias[col] + toF(resid[(size_t)row * 256 + col]);
                    int t = row & 63, n = row >> 6;
                    outF[((size_t)t * NN_ + n) * 256 + col] = v;
                }
    } else if (EPI == E_TRI) {
        // dbc[M,48]: cols 0-15 d1, 16-31 Bm, 32-47 Cm
#pragma unroll
        for (int mi = 0; mi < 4; mi++)
#pragma unroll
            for (int ni = 0; ni < 4; ni++)
#pragma unroll
                for (int r = 0; r < 4; r++) {
                    int row = m0 + wid * 64 + mi * 16 + (lane >> 4) * 4 + r;
                    int col = ni * 16 + (lane & 15);
                    if (col < 48) {
                        float v = acc[mi][ni][r] + bias[col];
                        outF[(size_t)row * 48 + col] = v;
                    }
                }
    } else {
        // E_LN1 / E_LN2: relu -> Cs, then row LN(s). BM=64, BN=256, grid.y=1.
#pragma unroll
        for (int mi = 0; mi < 4; mi++)
#pragma unroll
            for (int ni = 0; ni < 4; ni++)
#pragma unroll
                for (int r = 0; r < 4; r++) {
                    int rl = mi * 16 + (lane >> 4) * 4 + r;
                    int cl = wc * 64 + ni * 16 + (lane & 15);
                    Cs[rl * 260 + cl] = fmaxf(acc[mi][ni][r] + bias[cl], 0.f);
                }
        __syncthreads();
        float g1v[4], b1v[4], g2v[4], b2v[4];
#pragma unroll
        for (int i = 0; i < 4; i++) {
            g1v[i] = g1[lane * 4 + i];
            b1v[i] = b1[lane * 4 + i];
            if (EPI == E_LN2) { g2v[i] = g2[lane * 4 + i]; b2v[i] = b2[lane * 4 + i]; }
        }
        for (int rr = 0; rr < 16; rr++) {
            int rl = wid * 16 + rr;
            int grow = m0 + rl;
            float x[4];
#pragma unroll
            for (int i = 0; i < 4; i++) x[i] = Cs[rl * 260 + lane * 4 + i];
            float s = x[0] + x[1] + x[2] + x[3];
#pragma unroll
            for (int o = 1; o < 64; o <<= 1) s += __shfl_xor(s, o, 64);
            float mu = s * (1.f / 256.f);
            float d[4], ss = 0.f;
#pragma unroll
            for (int i = 0; i < 4; i++) { d[i] = x[i] - mu; ss = fmaf(d[i], d[i], ss); }
#pragma unroll
            for (int o = 1; o < 64; o <<= 1) ss += __shfl_xor(ss, o, 64);
            float inv = rsqrtf(fmaxf(ss * (1.f / 256.f), 0.f) + 1e-5f);
            float y[4];
#pragma unroll
            for (int i = 0; i < 4; i++) y[i] = d[i] * inv * g1v[i] + b1v[i];
            if (EPI == E_LN1) {
                __align__(8) bf16 pk[4];
#pragma unroll
                for (int i = 0; i < 4; i++) pk[i] = f2b(y[i]);
                *(s16x4*)&outB[(size_t)grow * 256 + lane * 4] = *(s16x4*)pk;
            } else {
                int trow = (grow & 1023) * 64 + (grow >> 10);   // [N,T] order
                __align__(8) bf16 pk[4];
#pragma unroll
                for (int i = 0; i < 4; i++) pk[i] = f2b(y[i]);
                *(s16x4*)&outB[(size_t)trow * 256 + lane * 4] = *(s16x4*)pk;
                float s2 = y[0] + y[1] + y[2] + y[3];
#pragma unroll
                for (int o = 1; o < 64; o <<= 1) s2 += __shfl_xor(s2, o, 64);
                float mu2 = s2 * (1.f / 256.f);
                float d2[4], ss2 = 0.f;
#pragma unroll
                for (int i = 0; i < 4; i++) { d2[i] = y[i] - mu2; ss2 = fmaf(d2[i], d2[i], ss2); }
#pragma unroll
                for (int o = 1; o < 64; o <<= 1) ss2 += __shfl_xor(ss2, o, 64);
                float inv2 = rsqrtf(fmaxf(ss2 * (1.f / 256.f), 0.f) + 1e-5f);
                __align__(8) bf16 pk2[4];
#pragma unroll
                for (int i = 0; i < 4; i++) pk2[i] = f2b(d2[i] * inv2 * g2v[i] + b2v[i]);
                *(s16x4*)&outB2[(size_t)trow * 256 + lane * 4] = *(s16x4*)pk2;
            }
        }
    }
}

// ---------------- adj bit-pack: adj in {0,1} -> 1 bit/elem (268MB -> 8.4MB) --------
// Per-thread packing: each thread builds one uint32 from 8 independent float4 loads
// (128B in flight/thread; no cross-lane ops, no serializing ballot). Bit 4i+c of
// word w = (adj[w*32 + 4i + c] != 0) -- identical little-endian bit order to the
// previous ballot version, so aggmm_k's byte reads are unchanged (bit-exact).
__global__ __launch_bounds__(256) void packadj_k(
    const float4* __restrict__ adj4, unsigned int* __restrict__ bits32)
{
    const size_t nwords = (size_t)TT * NN_ * NN_ / 32;   // 2,097,152
    const size_t stride = (size_t)gridDim.x * 256;
    for (size_t w = (size_t)blockIdx.x * 256 + threadIdx.x; w < nwords; w += stride) {
        const float4* __restrict__ p = adj4 + w * 8;
        float4 v[8];
#pragma unroll
        for (int i = 0; i < 8; i++) v[i] = p[i];
        unsigned int m = 0;
#pragma unroll
        for (int i = 0; i < 8; i++) {
            m |= (v[i].x != 0.f ? 1u : 0u) << (4 * i);
            m |= (v[i].y != 0.f ? 2u : 0u) << (4 * i);
            m |= (v[i].z != 0.f ? 4u : 0u) << (4 * i);
            m |= (v[i].w != 0.f ? 8u : 0u) << (4 * i);
        }
        bits32[w] = m;
    }
}

// ---------------- dense MFMA aggregation via bitmask -------------------------------
// adj in {0,1}: A-tile element = bit ? (GATED ? gate_bf16 : 1.0bf) : 0 -- bit-exact
// with f2b(adj*gate). Per K-step staging: 1 byte (adj bits) + s16x8 gates + s16x8 B.
// All staged data is L2/L3-resident (bits 8.4MB, gates 2MB, msgsT 512KB/t).
// BM=128 x BN=256, 4 waves (wave tile 64x128), 1-deep register prefetch.
template <bool GATED>
__global__ __launch_bounds__(256, 2) void aggmm_k(
    const unsigned char* __restrict__ adjbits, const bf16* __restrict__ gatesb,
    const bf16* __restrict__ BTsrc, bf16* __restrict__ out)
{
    __shared__ __align__(16) short As[128 * 40];
    __shared__ __align__(16) short Bs[256 * 40];
    const int tid = threadIdx.x;
    const int wid = tid >> 6, lane = tid & 63;
    const int wr = wid & 1;          // wave rows: wr*64
    const int wc = wid >> 1;         // wave cols: wc*128
    const int bx = blockIdx.x;
    const int t = bx >> 3, n0 = (bx & 7) * 128;
    const int srow = tid >> 2;       // 0..63
    const int skoff = (tid & 3) * 8; // 0,8,16,24

    // byte covering k-range [k0+skoff, k0+skoff+8) of row r: r*128 + k0/8 + (tid&3)
    const unsigned char* __restrict__ abB =
        adjbits + ((size_t)t * 1024 + n0) * 128 + (tid & 3);
    const bf16* __restrict__ gB = GATED ? (gatesb + (size_t)n0 * 1024 + skoff) : nullptr;
    const bf16* __restrict__ bt = GATED ? BTsrc : (BTsrc + (size_t)t * 256 * 1024);
    const size_t orow0 = (size_t)t * 1024 + n0;

    f32x4 acc[4][8] = {};

    unsigned char pm[2];
    s16x8 pg[2];
    s16x8 pb[4];

    auto LOADA = [&](int k0) {
#pragma unroll
        for (int c = 0; c < 2; c++) {
            int r = c * 64 + srow;
            pm[c] = abB[(size_t)r * 128 + (k0 >> 3)];
            if (GATED) pg[c] = *(const s16x8*)(gB + (size_t)r * 1024 + k0);
        }
#pragma unroll
        for (int c = 0; c < 4; c++)
            pb[c] = *(const s16x8*)(bt + (size_t)(c * 64 + srow) * 1024 + k0 + skoff);
    };
    auto STORE = [&]() {
#pragma unroll
        for (int c = 0; c < 2; c++) {
            unsigned m = pm[c];
            s16x8 tmp;
            if (GATED) {
#pragma unroll
                for (int i = 0; i < 8; i++) tmp[i] = ((m >> i) & 1) ? pg[c][i] : (short)0;
            } else {
#pragma unroll
                for (int i = 0; i < 8; i++) tmp[i] = ((m >> i) & 1) ? (short)0x3F80 : (short)0;
            }
            *(s16x8*)&As[(c * 64 + srow) * 40 + skoff] = tmp;
        }
#pragma unroll
        for (int c = 0; c < 4; c++)
            *(s16x8*)&Bs[(c * 64 + srow) * 40 + skoff] = pb[c];
    };

    LOADA(0);
#pragma unroll 1
    for (int k0 = 0; k0 < 1024; k0 += 32) {
        STORE();
        __syncthreads();
        if (k0 + 32 < 1024) LOADA(k0 + 32);   // next tile in flight during MFMA
        s16x8 af[4];
#pragma unroll
        for (int mi = 0; mi < 4; mi++)
            af[mi] = *(s16x8*)&As[(wr * 64 + mi * 16 + (lane & 15)) * 40 + (lane >> 4) * 8];
#pragma unroll
        for (int ni = 0; ni < 8; ni++) {
            s16x8 bfv = *(s16x8*)&Bs[(wc * 128 + ni * 16 + (lane & 15)) * 40 + (lane >> 4) * 8];
#pragma unroll
            for (int mi = 0; mi < 4; mi++)
                acc[mi][ni] = __builtin_amdgcn_mfma_f32_16x16x32_bf16(
                    af[mi], bfv, acc[mi][ni], 0, 0, 0);
        }
        __syncthreads();
    }

#pragma unroll
    for (int mi = 0; mi < 4; mi++)
#pragma unroll
        for (int ni = 0; ni < 8; ni++)
#pragma unroll
            for (int r = 0; r < 4; r++) {
                int rowl = wr * 64 + mi * 16 + (lane >> 4) * 4 + r;
                int col = wc * 128 + ni * 16 + (lane & 15);
                out[(orow0 + rowl) * 256 + col] = f2b(acc[mi][ni][r]);
            }
}

// ---------------- Mamba selective scan (block = n, thread = e) ----------------------
// dbc[M,48] rows: [d1(16) | Bm(16) | Cm(16)]. n = blockIdx -> dbc reads are
// wave-uniform (s_load). al[] pre-folds log2e so the hot loop is mul+v_exp per s.
// 4-way trees break the serial fma chains; unroll 2 overlaps t+1 proj with t update.
__global__ __launch_bounds__(512) void scan_k(
    const bf16* __restrict__ u, const bf16* __restrict__ sg,
    const float* __restrict__ dbc,
    const float* __restrict__ Wdt, const float* __restrict__ bdt,
    const float* __restrict__ Alog, const float* __restrict__ D,
    bf16* __restrict__ yg)
{
    const int n = blockIdx.x, e = threadIdx.x;
    float al[16], wdt[16], h[16];
#pragma unroll
    for (int s = 0; s < 16; s++) {
        al[s] = -__expf(Alog[e * 16 + s]) * 1.44269504f;   // * log2(e)
        h[s] = 0.f;
    }
#pragma unroll
    for (int k = 0; k < 16; k++) wdt[k] = Wdt[(size_t)k * EE + e];
    const float bdte = bdt[e], De = D[e];
    const float* __restrict__ rowp = dbc + (size_t)n * TT * 48;
    const size_t base = (size_t)n * TT * EE + e;
#pragma unroll 2
    for (int t = 0; t < TT; t++) {
        const float* __restrict__ r = rowp + t * 48;
        float a0 = bdte, a1 = 0.f, a2 = 0.f, a3 = 0.f;
#pragma unroll
        for (int k = 0; k < 4; k++) {
            a0 = fmaf(r[k],      wdt[k],      a0);
            a1 = fmaf(r[k + 4],  wdt[k + 4],  a1);
            a2 = fmaf(r[k + 8],  wdt[k + 8],  a2);
            a3 = fmaf(r[k + 12], wdt[k + 12], a3);
        }
        float acc = (a0 + a1) + (a2 + a3);
        float delta = (acc > 20.f)
            ? acc
            : 0.69314718056f * LOG2F(1.f + EXP2F(acc * 1.44269504f));
        size_t idx = base + (size_t)t * EE;
        float uv = toF(u[idx]);
        float du = delta * uv;
        float y0 = 0.f, y1 = 0.f, y2 = 0.f, y3 = 0.f;
#pragma unroll
        for (int s = 0; s < 16; s += 4) {
            float ad0 = EXP2F(delta * al[s]);
            float ad1 = EXP2F(delta * al[s + 1]);
            float ad2 = EXP2F(delta * al[s + 2]);
            float ad3 = EXP2F(delta * al[s + 3]);
            h[s]     = fmaf(ad0, h[s],     du * r[16 + s]);
            h[s + 1] = fmaf(ad1, h[s + 1], du * r[17 + s]);
            h[s + 2] = fmaf(ad2, h[s + 2], du * r[18 + s]);
            h[s + 3] = fmaf(ad3, h[s + 3], du * r[19 + s]);
            y0 = fmaf(r[32 + s], h[s],     y0);
            y1 = fmaf(r[33 + s], h[s + 1], y1);
            y2 = fmaf(r[34 + s], h[s + 2], y2);
            y3 = fmaf(r[35 + s], h[s + 3], y3);
        }
        float y = (y0 + y1) + (y2 + y3);
        yg[idx] = f2b((y + uv * De) * toF(sg[idx]));
    }
}

// ---------------- prep kernels ------------------------------------------------------
__global__ void cast_k(const float* __restrict__ in, bf16* __restrict__ out, int n) {
    int i = blockIdx.x * 256 + threadIdx.x;
    if (i < n) out[i] = f2b(in[i]);
}
__global__ void transT_k(const float* __restrict__ W, bf16* __restrict__ out, int K, int Nn) {
    int gid = blockIdx.x * 256 + threadIdx.x;
    if (gid >= K * Nn) return;
    int n = gid / K, k = gid - n * K;
    out[gid] = f2b(W[(size_t)k * Nn + n]);
}
__global__ void transmsgs_k(const float* __restrict__ msgs, bf16* __restrict__ msgsT) {
    int gid = blockIdx.x * 256 + threadIdx.x;
    int c = gid >> 10, j = gid & 1023;
    msgsT[gid] = f2b(msgs[(size_t)j * 256 + c]);
}
__global__ void wdbct_k(const float* __restrict__ Wd, const float* __restrict__ WB,
                        const float* __restrict__ WC, bf16* __restrict__ out,
                        const float* __restrict__ bd, const float* __restrict__ bB,
                        const float* __restrict__ bC, float* __restrict__ biascat) {
    int gid = blockIdx.x * 256 + threadIdx.x;
    if (gid < 48) biascat[gid] = (gid < 16) ? bd[gid] : (gid < 32) ? bB[gid - 16] : bC[gid - 32];
    if (gid >= 64 * 512) return;
    int n = gid >> 9, k = gid & 511;
    float v = 0.f;
    if (n < 16)      v = Wd[(size_t)k * 16 + n];
    else if (n < 32) v = WB[(size_t)k * 16 + (n - 16)];
    else if (n < 48) v = WC[(size_t)k * 16 + (n - 32)];
    out[gid] = f2b(v);
}

extern "C" void kernel_launch(void* const* d_in, const int* in_sizes, int n_in,
                              void* d_out, int out_size, void* d_ws, size_t ws_size,
                              hipStream_t stream)
{
    const float* adj   = (const float*)d_in[0];
    const float* pos   = (const float*)d_in[1];
    const float* g1Wm  = (const float*)d_in[2];
    const float* g1bm  = (const float*)d_in[3];
    const float* g1Wq  = (const float*)d_in[4];
    const float* g1Wk  = (const float*)d_in[5];
    const float* g1gb  = (const float*)d_in[6];
    const float* g1Wu  = (const float*)d_in[7];
    const float* g1bu  = (const float*)d_in[8];
    const float* g1lg  = (const float*)d_in[9];
    const float* g1lb  = (const float*)d_in[10];
    const float* g2Wm  = (const float*)d_in[11];
    const float* g2bm  = (const float*)d_in[12];
    const float* g2Wu  = (const float*)d_in[13];
    const float* g2bu  = (const float*)d_in[14];
    const float* g2lg  = (const float*)d_in[15];
    const float* g2lb  = (const float*)d_in[16];
    const float* mlg   = (const float*)d_in[17];
    const float* mlb   = (const float*)d_in[18];
    const float* mWin  = (const float*)d_in[19];
    const float* mbin  = (const float*)d_in[20];
    const float* mWd   = (const float*)d_in[21];
    const float* mbd   = (const float*)d_in[22];
    const float* mWdt  = (const float*)d_in[23];
    const float* mbdt  = (const float*)d_in[24];
    const float* mWB   = (const float*)d_in[25];
    const float* mbB   = (const float*)d_in[26];
    const float* mWC   = (const float*)d_in[27];
    const float* mbC   = (const float*)d_in[28];
    const float* mAlog = (const float*)d_in[29];
    const float* mD    = (const float*)d_in[30];
    const float* mWout = (const float*)d_in[31];
    const float* mbout = (const float*)d_in[32];
    float* out = (float*)d_out;
    char* ws = (char*)d_ws;

    const size_t BIGE = (size_t)TT * NN_ * 256;
    size_t o = 0;
    auto alloc = [&](size_t bytes) { size_t r = o; o += (bytes + 255) & ~(size_t)255; return r; };

    float* msgs  = (float*)(ws + alloc((size_t)NN_ * 256 * 4));
    float* q     = (float*)(ws + alloc((size_t)NN_ * 256 * 4));
    float* kk    = (float*)(ws + alloc((size_t)NN_ * 256 * 4));
    bf16*  gatesb = (bf16*)(ws + alloc((size_t)NN_ * NN_ * 2));
    unsigned long long* adjbits =
        (unsigned long long*)(ws + alloc((size_t)TT * NN_ * NN_ / 8));
    bf16*  Ra    = (bf16*)(ws + alloc(BIGE * 2));                 // agg / xn
    size_t off_x1 = alloc(BIGE * 2);
    bf16*  x1    = (bf16*)(ws + off_x1);
    bf16*  agg2  = (bf16*)(ws + alloc(BIGE * 2));                 // contiguous after x1
    bf16*  x2    = (bf16*)(ws + alloc(BIGE * 2));                 // res, [N,T,H]
    bf16*  yg    = (bf16*)(ws + alloc(BIGE * 2));
    bf16*  sg    = (bf16*)(ws + alloc((size_t)NN_ * TT * EE * 2));
    float* dbc   = (float*)(ws + alloc((size_t)TT * NN_ * 48 * 4));  // [M,48] d1|Bm|Cm
    bf16*  u     = (bf16*)(ws + off_x1);                          // aliases x1+agg2
    // transposed bf16 weights / staging
    bf16* posb   = (bf16*)(ws + alloc((size_t)NN_ * 256 * 2));
    bf16* g1WuT  = (bf16*)(ws + alloc((size_t)256 * 512 * 2));
    bf16* g2WmT  = (bf16*)(ws + alloc((size_t)256 * 256 * 2));
    bf16* g2WuT  = (bf16*)(ws + alloc((size_t)256 * 512 * 2));
    bf16* mWinT  = (bf16*)(ws + alloc((size_t)1024 * 256 * 2));
    bf16* mWoutT = (bf16*)(ws + alloc((size_t)256 * 512 * 2));
    bf16* WdBCT  = (bf16*)(ws + alloc((size_t)64 * 512 * 2));
    float* biascat = (float*)(ws + alloc(64 * 4));
    bf16* msgsT  = (bf16*)(ws + alloc((size_t)256 * 1024 * 2));
    bf16* msgs2T = (bf16*)(ws + alloc(BIGE * 2));

    const unsigned ALLR = 0xFFFFFFFFu;
    const int M = TT * NN_;

    // prep
    packadj_k<<<2048, 256, 0, stream>>>((const float4*)adj, (unsigned int*)adjbits);
    cast_k<<<NN_, 256, 0, stream>>>(pos, posb, NN_ * 256);
    transT_k<<<(512 * 256 + 255) / 256, 256, 0, stream>>>(g1Wu, g1WuT, 512, 256);
    transT_k<<<(256 * 256 + 255) / 256, 256, 0, stream>>>(g2Wm, g2WmT, 256, 256);
    transT_k<<<(512 * 256 + 255) / 256, 256, 0, stream>>>(g2Wu, g2WuT, 512, 256);
    transT_k<<<(256 * 1024 + 255) / 256, 256, 0, stream>>>(mWin, mWinT, 256, 1024);
    transT_k<<<(512 * 256 + 255) / 256, 256, 0, stream>>>(mWout, mWoutT, 512, 256);
    wdbct_k<<<(64 * 512 + 255) / 256, 256, 0, stream>>>(mWd, mWB, mWC, WdBCT, mbd, mbB, mbC, biascat);

    // S0: msgs = pos @ g1_Wm + bm (f32)
    gemm_k<false, EPI_F32><<<dim3(16, 4), 256, 0, stream>>>(
        pos, g1Wm, msgs, g1bm, nullptr, 1.f, NN_, 256, 256, 256, 256);
    transmsgs_k<<<1024, 256, 0, stream>>>(msgs, msgsT);
    // S1: q, k
    gemm_k<false, EPI_F32><<<dim3(16, 4), 256, 0, stream>>>(
        msgs, g1Wq, q, nullptr, nullptr, 1.f, NN_, 256, 256, 256, 256);
    gemm_k<false, EPI_F32><<<dim3(16, 4), 256, 0, stream>>>(
        msgs, g1Wk, kk, nullptr, nullptr, 1.f, NN_, 256, 256, 256, 256);
    // S2: gates = sigmoid(q @ k^T / 16 + gb) -> bf16 (exact wrt old f2b(adj*gate))
    gemm_k<true, EPI_SIG_B16><<<dim3(16, 16), 256, 0, stream>>>(
        q, kk, (float*)gatesb, nullptr, g1gb, 1.f / 16.f, NN_, NN_, 256, 256, 256);
    // S3: agg -> Ra
    aggmm_k<true><<<512, 256, 0, stream>>>(
        (const unsigned char*)adjbits, gatesb, msgsT, Ra);
    // S4(+S5): x1 = LN(relu(cat(posb,Ra) @ Wu1 + bu1))
    mfma_k<64, 256, true, E_LN1><<<dim3(1024, 1), 256, 0, stream>>>(
        posb, Ra, 1023u, g1WuT, g1bu, nullptr, x1, nullptr,
        g1lg, g1lb, nullptr, nullptr, nullptr, M, 512);
    // S6: msgs2 = x1 @ Wm2 + bm2 -> msgs2T ([t][c][j])
    mfma_k<64, 256, false, E_BF16T><<<dim3(1024, 1), 256, 0, stream>>>(
        x1, x1, ALLR, g2WmT, g2bm, nullptr, msgs2T, nullptr,
        nullptr, nullptr, nullptr, nullptr, nullptr, M, 256);
    // S7: agg2 = adj @ msgs2
    aggmm_k<false><<<512, 256, 0, stream>>>(
        (const unsigned char*)adjbits, nullptr, msgs2T, agg2);
    // S8(+S9+S10): x2 = LN(relu(cat(x1,agg2)@Wu2+bu2)) [N,T,H], xn = LN2 -> Ra [N,T,H]
    mfma_k<64, 256, true, E_LN2><<<dim3(1024, 1), 256, 0, stream>>>(
        x1, agg2, ALLR, g2WuT, g2bu, nullptr, x2, Ra,
        g2lg, g2lb, mlg, mlb, nullptr, M, 512);
    // S11: u/sg = silu halves of xn @ Win + bin
    mfma_k<64, 256, false, E_SILU><<<dim3(1024, 4), 256, 0, stream>>>(
        Ra, Ra, ALLR, mWinT, mbin, nullptr, u, sg,
        nullptr, nullptr, nullptr, nullptr, nullptr, M, 256);
    // S12 fused: dbc = u @ [Wd|WB|WC] + biases  ([M,48] interleaved)
    mfma_k<256, 64, false, E_TRI><<<dim3(256, 1), 256, 0, stream>>>(
        u, u, ALLR, WdBCT, biascat, dbc, nullptr, nullptr,
        nullptr, nullptr, nullptr, nullptr, nullptr, M, 512);
    // S13: selective scan -> yg  (block per n, thread per e)
    scan_k<<<NN_, 512, 0, stream>>>(u, sg, dbc, mWdt, mbdt, mAlog, mD, yg);
    // S14: out = yg @ Wout + bout + res -> [T,N,H] f32
    mfma_k<64, 256, false, E_OUT><<<dim3(1024, 1), 256, 0, stream>>>(
        yg, yg, ALLR, mWoutT, mbout, out, nullptr, nullptr,
        nullptr, nullptr, nullptr, nullptr, x2, M, 512);

    (void)in_sizes; (void)n_in; (void)out_size; (void)ws_size;
}

// Round 4
// 1063.268 us; speedup vs baseline: 1.0817x; 1.0112x over previous
//
#include <hip/hip_runtime.h>
#include <hip/hip_bf16.h>

typedef __hip_bfloat16 bf16;
typedef __attribute__((ext_vector_type(8))) short s16x8;
typedef __attribute__((ext_vector_type(4))) short s16x4;
typedef __attribute__((ext_vector_type(4))) float f32x4;

#define TT 64
#define NN_ 1024
#define EE 512

__device__ __forceinline__ float toF(float v) { return v; }
__device__ __forceinline__ float toF(bf16 v) { return __bfloat162float(v); }
__device__ __forceinline__ bf16 f2b(float v) { return __float2bfloat16(v); }

#if __has_builtin(__builtin_amdgcn_exp2f)
#define EXP2F(x) __builtin_amdgcn_exp2f(x)
#else
#define EXP2F(x) exp2f(x)
#endif
#if __has_builtin(__builtin_amdgcn_logf)
#define LOG2F(x) __builtin_amdgcn_logf(x)
#else
#define LOG2F(x) log2f(x)
#endif

enum { EPI_F32 = 0, EPI_SIG_F32 = 1, EPI_SIG_B16 = 2 };
enum { E_LN1 = 0, E_BF16 = 1, E_LN2 = 2, E_SILU = 3, E_OUT = 4, E_TRI = 5, E_BF16T = 6 };

// ---------------- small fp32 tiled GEMM (S0-S2 only; 1024-row problems) -------------
template <bool TRANSB, int EPI>
__global__ __launch_bounds__(256) void gemm_k(
    const float* __restrict__ A, const float* __restrict__ B,
    float* __restrict__ outF, const float* __restrict__ bias,
    const float* __restrict__ sbeta, float alpha,
    int M, int Nn, int K, int lda, int ldb)
{
    __shared__ float As[16][68];
    __shared__ float Bs[16][68];
    const int tid = threadIdx.x;
    const int tx = tid & 15, ty = tid >> 4;
    const int m0 = blockIdx.x * 64, n0 = blockIdx.y * 64;
    float acc[4][4] = {};

    for (int k0 = 0; k0 < K; k0 += 16) {
        {
            int row = tid >> 2, kk0 = (tid & 3) * 4, grow = m0 + row;
#pragma unroll
            for (int j = 0; j < 4; j++) {
                int kk = kk0 + j, gk = k0 + kk;
                As[kk][row] = (grow < M) ? A[(size_t)grow * lda + gk] : 0.f;
            }
        }
        if (!TRANSB) {
            int kk = tid >> 4, c0 = (tid & 15) * 4;
#pragma unroll
            for (int j = 0; j < 4; j++) {
                int col = c0 + j, gn = n0 + col;
                Bs[kk][col] = (gn < Nn) ? B[(size_t)(k0 + kk) * ldb + gn] : 0.f;
            }
        } else {
            int col = tid >> 2, kk0 = (tid & 3) * 4, gn = n0 + col;
#pragma unroll
            for (int j = 0; j < 4; j++) {
                int kk = kk0 + j;
                Bs[kk][col] = (gn < Nn) ? B[(size_t)gn * ldb + (k0 + kk)] : 0.f;
            }
        }
        __syncthreads();
#pragma unroll
        for (int kk = 0; kk < 16; kk++) {
            float a[4], b[4];
#pragma unroll
            for (int i = 0; i < 4; i++) a[i] = As[kk][ty * 4 + i];
#pragma unroll
            for (int j = 0; j < 4; j++) b[j] = Bs[kk][tx * 4 + j];
#pragma unroll
            for (int i = 0; i < 4; i++)
#pragma unroll
                for (int j = 0; j < 4; j++)
                    acc[i][j] = fmaf(a[i], b[j], acc[i][j]);
        }
        __syncthreads();
    }

    float gb = (EPI != EPI_F32 && sbeta) ? sbeta[0] : 0.f;
#pragma unroll
    for (int i = 0; i < 4; i++) {
        int row = m0 + ty * 4 + i;
        if (row >= M) continue;
#pragma unroll
        for (int j = 0; j < 4; j++) {
            int col = n0 + tx * 4 + j;
            if (col >= Nn) continue;
            float v = acc[i][j];
            if (EPI == EPI_F32) {
                if (bias) v += bias[col];
                outF[(size_t)row * Nn + col] = v;
            } else if (EPI == EPI_SIG_F32) {
                v = v * alpha + gb;
                outF[(size_t)row * Nn + col] = 1.f / (1.f + __expf(-v));
            } else {
                v = v * alpha + gb;
                ((bf16*)outF)[(size_t)row * Nn + col] = f2b(1.f / (1.f + __expf(-v)));
            }
        }
    }
}

// ---------------- MFMA bf16 GEMM -----------------------------------------------------
// C[M,Nn] = A[M,K](bf16) @ BT[Nn,K]^T(bf16), fp32 accum, fused epilogues.
// 256 threads = 4 waves. BK=32. BN=256: waves side-by-side; BM=256/BN=64: stacked.
// CAT: A row r = [A1[(r&rowmask),0:256] | A2[r,0:256]], K=512.
// 1-deep register prefetch: next K-tile's global loads issue right after the first
// barrier so they fly during MFMA (same transform that won ~25% on aggmm_k).
template <int BM, int BN, bool CAT, int EPI>
__global__ __launch_bounds__(256) void mfma_k(
    const bf16* __restrict__ A1, const bf16* __restrict__ A2, unsigned rowmask,
    const bf16* __restrict__ BT, const float* __restrict__ bias,
    float* __restrict__ outF,
    bf16* __restrict__ outB, bf16* __restrict__ outB2,
    const float* __restrict__ g1, const float* __restrict__ b1,
    const float* __restrict__ g2, const float* __restrict__ b2,
    const bf16* __restrict__ resid,
    int M, int K)
{
    constexpr bool LN = (EPI == E_LN1 || EPI == E_LN2);
    constexpr int STAGE_B = (BM * 32 + BN * 32) * 2;
    constexpr int TRB = (EPI == E_BF16T) ? (64 * 268 * 2) : 0;
    constexpr int SB = LN ? (64 * 260 * 4) : (STAGE_B > TRB ? STAGE_B : TRB);
    __shared__ __align__(16) char smem[SB];
    short* As = (short*)smem;
    short* Bs = As + BM * 32;
    float* Cs = (float*)smem;   // LN epilogue reuses staging LDS

    const int tid = threadIdx.x;
    const int wid = tid >> 6, lane = tid & 63;
    const int wr = (BN == 256) ? 0 : wid;
    const int wc = (BN == 256) ? wid : 0;
    const int m0 = blockIdx.x * BM, n0 = blockIdx.y * BN;
    const int srow = tid >> 2;
    const int skoff = (tid & 3) * 8;

    f32x4 acc[4][4] = {};
    s16x8 pa[BM / 64], pbv[BN / 64];

    auto LOADT = [&](int k0) {
#pragma unroll
        for (int c = 0; c < BM / 64; c++) {
            int r = c * 64 + srow;
            int gr = m0 + r;
            const bf16* p;
            if (CAT) {
                int gk = k0 + skoff;
                p = (gk < 256) ? (A1 + (size_t)(gr & rowmask) * 256 + gk)
                               : (A2 + (size_t)gr * 256 + (gk - 256));
            } else {
                p = A1 + (size_t)gr * K + k0 + skoff;
            }
            pa[c] = *(const s16x8*)p;
        }
#pragma unroll
        for (int c = 0; c < BN / 64; c++) {
            int r = c * 64 + srow;
            pbv[c] = *(const s16x8*)(BT + (size_t)(n0 + r) * K + k0 + skoff);
        }
    };

    LOADT(0);
#pragma unroll 1
    for (int k0 = 0; k0 < K; k0 += 32) {
#pragma unroll
        for (int c = 0; c < BM / 64; c++)
            *(s16x8*)&As[(c * 64 + srow) * 32 + skoff] = pa[c];
#pragma unroll
        for (int c = 0; c < BN / 64; c++)
            *(s16x8*)&Bs[(c * 64 + srow) * 32 + skoff] = pbv[c];
        __syncthreads();
        if (k0 + 32 < K) LOADT(k0 + 32);   // next tile in flight during MFMA
        s16x8 af[4], bf[4];
#pragma unroll
        for (int mi = 0; mi < 4; mi++)
            af[mi] = *(s16x8*)&As[(wr * 64 + mi * 16 + (lane & 15)) * 32 + (lane >> 4) * 8];
#pragma unroll
        for (int ni = 0; ni < 4; ni++)
            bf[ni] = *(s16x8*)&Bs[(wc * 64 + ni * 16 + (lane & 15)) * 32 + (lane >> 4) * 8];
#pragma unroll
        for (int mi = 0; mi < 4; mi++)
#pragma unroll
            for (int ni = 0; ni < 4; ni++)
                acc[mi][ni] = __builtin_amdgcn_mfma_f32_16x16x32_bf16(
                    af[mi], bf[ni], acc[mi][ni], 0, 0, 0);
        __syncthreads();
    }

    if (EPI == E_SILU) {
#pragma unroll
        for (int mi = 0; mi < 4; mi++)
#pragma unroll
            for (int ni = 0; ni < 4; ni++)
#pragma unroll
                for (int r = 0; r < 4; r++) {
                    int row = m0 + wr * 64 + mi * 16 + (lane >> 4) * 4 + r;
                    int col = n0 + wc * 64 + ni * 16 + (lane & 15);
                    float v = acc[mi][ni][r] + bias[col];
                    float s = v / (1.f + __expf(-v));
                    if (col < EE) outB[(size_t)row * EE + col] = f2b(s);
                    else          outB2[(size_t)row * EE + (col - EE)] = f2b(s);
                }
    } else if (EPI == E_BF16) {
#pragma unroll
        for (int mi = 0; mi < 4; mi++)
#pragma unroll
            for (int ni = 0; ni < 4; ni++)
#pragma unroll
                for (int r = 0; r < 4; r++) {
                    int row = m0 + wr * 64 + mi * 16 + (lane >> 4) * 4 + r;
                    int col = n0 + wc * 64 + ni * 16 + (lane & 15);
                    outB[(size_t)row * 256 + col] = f2b(acc[mi][ni][r] + bias[col]);
                }
    } else if (EPI == E_BF16T) {
        // rows r = t*1024+j -> store transposed [t][col][j].
        // Stage the 64x256 tile in LDS (pad 268 shorts: conflict-clean), then each
        // thread owns one col and writes 4x16B contiguous runs (vs 2B scatter).
        short* Ts = (short*)smem;
#pragma unroll
        for (int mi = 0; mi < 4; mi++)
#pragma unroll
            for (int ni = 0; ni < 4; ni++)
#pragma unroll
                for (int r = 0; r < 4; r++) {
                    int rl = mi * 16 + (lane >> 4) * 4 + r;
                    int cl = wc * 64 + ni * 16 + (lane & 15);
                    union { bf16 b; short s; } u;
                    u.b = f2b(acc[mi][ni][r] + bias[cl]);
                    Ts[rl * 268 + cl] = u.s;
                }
        __syncthreads();
        const int col = tid;
        size_t dbase = (((size_t)(m0 >> 10)) * 256 + col) * 1024 + (m0 & 1023);
#pragma unroll
        for (int j0 = 0; j0 < 64; j0 += 8) {
            s16x8 v;
#pragma unroll
            for (int i = 0; i < 8; i++) v[i] = Ts[(j0 + i) * 268 + col];
            *(s16x8*)&outB[dbase + j0] = v;
        }
    } else if (EPI == E_OUT) {
#pragma unroll
        for (int mi = 0; mi < 4; mi++)
#pragma unroll
            for (int ni = 0; ni < 4; ni++)
#pragma unroll
                for (int r = 0; r < 4; r++) {
                    int row = m0 + wr * 64 + mi * 16 + (lane >> 4) * 4 + r;
                    int col = n0 + wc * 64 + ni * 16 + (lane & 15);
                    float v = acc[mi][ni][r] + bias[col] + toF(resid[(size_t)row * 256 + col]);
                    int t = row & 63, n = row >> 6;
                    outF[((size_t)t * NN_ + n) * 256 + col] = v;
                }
    } else if (EPI == E_TRI) {
        // dbc[M,48]: cols 0-15 d1, 16-31 Bm, 32-47 Cm
#pragma unroll
        for (int mi = 0; mi < 4; mi++)
#pragma unroll
            for (int ni = 0; ni < 4; ni++)
#pragma unroll
                for (int r = 0; r < 4; r++) {
                    int row = m0 + wid * 64 + mi * 16 + (lane >> 4) * 4 + r;
                    int col = ni * 16 + (lane & 15);
                    if (col < 48) {
                        float v = acc[mi][ni][r] + bias[col];
                        outF[(size_t)row * 48 + col] = v;
                    }
                }
    } else {
        // E_LN1 / E_LN2: relu -> Cs, then row LN(s). BM=64, BN=256, grid.y=1.
#pragma unroll
        for (int mi = 0; mi < 4; mi++)
#pragma unroll
            for (int ni = 0; ni < 4; ni++)
#pragma unroll
                for (int r = 0; r < 4; r++) {
                    int rl = mi * 16 + (lane >> 4) * 4 + r;
                    int cl = wc * 64 + ni * 16 + (lane & 15);
                    Cs[rl * 260 + cl] = fmaxf(acc[mi][ni][r] + bias[cl], 0.f);
                }
        __syncthreads();
        float g1v[4], b1v[4], g2v[4], b2v[4];
#pragma unroll
        for (int i = 0; i < 4; i++) {
            g1v[i] = g1[lane * 4 + i];
            b1v[i] = b1[lane * 4 + i];
            if (EPI == E_LN2) { g2v[i] = g2[lane * 4 + i]; b2v[i] = b2[lane * 4 + i]; }
        }
        for (int rr = 0; rr < 16; rr++) {
            int rl = wid * 16 + rr;
            int grow = m0 + rl;
            float x[4];
#pragma unroll
            for (int i = 0; i < 4; i++) x[i] = Cs[rl * 260 + lane * 4 + i];
            float s = x[0] + x[1] + x[2] + x[3];
#pragma unroll
            for (int o = 1; o < 64; o <<= 1) s += __shfl_xor(s, o, 64);
            float mu = s * (1.f / 256.f);
            float d[4], ss = 0.f;
#pragma unroll
            for (int i = 0; i < 4; i++) { d[i] = x[i] - mu; ss = fmaf(d[i], d[i], ss); }
#pragma unroll
            for (int o = 1; o < 64; o <<= 1) ss += __shfl_xor(ss, o, 64);
            float inv = rsqrtf(fmaxf(ss * (1.f / 256.f), 0.f) + 1e-5f);
            float y[4];
#pragma unroll
            for (int i = 0; i < 4; i++) y[i] = d[i] * inv * g1v[i] + b1v[i];
            if (EPI == E_LN1) {
                __align__(8) bf16 pk[4];
#pragma unroll
                for (int i = 0; i < 4; i++) pk[i] = f2b(y[i]);
                *(s16x4*)&outB[(size_t)grow * 256 + lane * 4] = *(s16x4*)pk;
            } else {
                int trow = (grow & 1023) * 64 + (grow >> 10);   // [N,T] order
                __align__(8) bf16 pk[4];
#pragma unroll
                for (int i = 0; i < 4; i++) pk[i] = f2b(y[i]);
                *(s16x4*)&outB[(size_t)trow * 256 + lane * 4] = *(s16x4*)pk;
                float s2 = y[0] + y[1] + y[2] + y[3];
#pragma unroll
                for (int o = 1; o < 64; o <<= 1) s2 += __shfl_xor(s2, o, 64);
                float mu2 = s2 * (1.f / 256.f);
                float d2[4], ss2 = 0.f;
#pragma unroll
                for (int i = 0; i < 4; i++) { d2[i] = y[i] - mu2; ss2 = fmaf(d2[i], d2[i], ss2); }
#pragma unroll
                for (int o = 1; o < 64; o <<= 1) ss2 += __shfl_xor(ss2, o, 64);
                float inv2 = rsqrtf(fmaxf(ss2 * (1.f / 256.f), 0.f) + 1e-5f);
                __align__(8) bf16 pk2[4];
#pragma unroll
                for (int i = 0; i < 4; i++) pk2[i] = f2b(d2[i] * inv2 * g2v[i] + b2v[i]);
                *(s16x4*)&outB2[(size_t)trow * 256 + lane * 4] = *(s16x4*)pk2;
            }
        }
    }
}

// ---------------- adj bit-pack: adj in {0,1} -> 1 bit/elem (268MB -> 8.4MB) --------
// Per-thread packing: each thread builds one uint32 from 8 independent float4 loads
// (128B in flight/thread; no cross-lane ops, no serializing ballot). Bit 4i+c of
// word w = (adj[w*32 + 4i + c] != 0) -- identical little-endian bit order to the
// previous ballot version, so aggmm_k's byte reads are unchanged (bit-exact).
__global__ __launch_bounds__(256) void packadj_k(
    const float4* __restrict__ adj4, unsigned int* __restrict__ bits32)
{
    const size_t nwords = (size_t)TT * NN_ * NN_ / 32;   // 2,097,152
    const size_t stride = (size_t)gridDim.x * 256;
    for (size_t w = (size_t)blockIdx.x * 256 + threadIdx.x; w < nwords; w += stride) {
        const float4* __restrict__ p = adj4 + w * 8;
        float4 v[8];
#pragma unroll
        for (int i = 0; i < 8; i++) v[i] = p[i];
        unsigned int m = 0;
#pragma unroll
        for (int i = 0; i < 8; i++) {
            m |= (v[i].x != 0.f ? 1u : 0u) << (4 * i);
            m |= (v[i].y != 0.f ? 2u : 0u) << (4 * i);
            m |= (v[i].z != 0.f ? 4u : 0u) << (4 * i);
            m |= (v[i].w != 0.f ? 8u : 0u) << (4 * i);
        }
        bits32[w] = m;
    }
}

// ---------------- dense MFMA aggregation via bitmask -------------------------------
// adj in {0,1}: A-tile element = bit ? (GATED ? gate_bf16 : 1.0bf) : 0 -- bit-exact
// with f2b(adj*gate). Per K-step staging: 1 byte (adj bits) + s16x8 gates + s16x8 B.
// All staged data is L2/L3-resident (bits 8.4MB, gates 2MB, msgsT 512KB/t).
// BM=128 x BN=256, 4 waves (wave tile 64x128), 1-deep register prefetch.
template <bool GATED>
__global__ __launch_bounds__(256, 2) void aggmm_k(
    const unsigned char* __restrict__ adjbits, const bf16* __restrict__ gatesb,
    const bf16* __restrict__ BTsrc, bf16* __restrict__ out)
{
    __shared__ __align__(16) short As[128 * 40];
    __shared__ __align__(16) short Bs[256 * 40];
    const int tid = threadIdx.x;
    const int wid = tid >> 6, lane = tid & 63;
    const int wr = wid & 1;          // wave rows: wr*64
    const int wc = wid >> 1;         // wave cols: wc*128
    const int bx = blockIdx.x;
    const int t = bx >> 3, n0 = (bx & 7) * 128;
    const int srow = tid >> 2;       // 0..63
    const int skoff = (tid & 3) * 8; // 0,8,16,24

    // byte covering k-range [k0+skoff, k0+skoff+8) of row r: r*128 + k0/8 + (tid&3)
    const unsigned char* __restrict__ abB =
        adjbits + ((size_t)t * 1024 + n0) * 128 + (tid & 3);
    const bf16* __restrict__ gB = GATED ? (gatesb + (size_t)n0 * 1024 + skoff) : nullptr;
    const bf16* __restrict__ bt = GATED ? BTsrc : (BTsrc + (size_t)t * 256 * 1024);
    const size_t orow0 = (size_t)t * 1024 + n0;

    f32x4 acc[4][8] = {};

    unsigned char pm[2];
    s16x8 pg[2];
    s16x8 pb[4];

    auto LOADA = [&](int k0) {
#pragma unroll
        for (int c = 0; c < 2; c++) {
            int r = c * 64 + srow;
            pm[c] = abB[(size_t)r * 128 + (k0 >> 3)];
            if (GATED) pg[c] = *(const s16x8*)(gB + (size_t)r * 1024 + k0);
        }
#pragma unroll
        for (int c = 0; c < 4; c++)
            pb[c] = *(const s16x8*)(bt + (size_t)(c * 64 + srow) * 1024 + k0 + skoff);
    };
    auto STORE = [&]() {
#pragma unroll
        for (int c = 0; c < 2; c++) {
            unsigned m = pm[c];
            s16x8 tmp;
            if (GATED) {
#pragma unroll
                for (int i = 0; i < 8; i++) tmp[i] = ((m >> i) & 1) ? pg[c][i] : (short)0;
            } else {
#pragma unroll
                for (int i = 0; i < 8; i++) tmp[i] = ((m >> i) & 1) ? (short)0x3F80 : (short)0;
            }
            *(s16x8*)&As[(c * 64 + srow) * 40 + skoff] = tmp;
        }
#pragma unroll
        for (int c = 0; c < 4; c++)
            *(s16x8*)&Bs[(c * 64 + srow) * 40 + skoff] = pb[c];
    };

    LOADA(0);
#pragma unroll 1
    for (int k0 = 0; k0 < 1024; k0 += 32) {
        STORE();
        __syncthreads();
        if (k0 + 32 < 1024) LOADA(k0 + 32);   // next tile in flight during MFMA
        s16x8 af[4];
#pragma unroll
        for (int mi = 0; mi < 4; mi++)
            af[mi] = *(s16x8*)&As[(wr * 64 + mi * 16 + (lane & 15)) * 40 + (lane >> 4) * 8];
#pragma unroll
        for (int ni = 0; ni < 8; ni++) {
            s16x8 bfv = *(s16x8*)&Bs[(wc * 128 + ni * 16 + (lane & 15)) * 40 + (lane >> 4) * 8];
#pragma unroll
            for (int mi = 0; mi < 4; mi++)
                acc[mi][ni] = __builtin_amdgcn_mfma_f32_16x16x32_bf16(
                    af[mi], bfv, acc[mi][ni], 0, 0, 0);
        }
        __syncthreads();
    }

#pragma unroll
    for (int mi = 0; mi < 4; mi++)
#pragma unroll
        for (int ni = 0; ni < 8; ni++)
#pragma unroll
            for (int r = 0; r < 4; r++) {
                int rowl = wr * 64 + mi * 16 + (lane >> 4) * 4 + r;
                int col = wc * 128 + ni * 16 + (lane & 15);
                out[(orow0 + rowl) * 256 + col] = f2b(acc[mi][ni][r]);
            }
}

// ---------------- Mamba selective scan (block = n-col x e-half) ---------------------
// dbc[M,48] rows: [d1(16) | Bm(16) | Cm(16)]. n = blockIdx.x -> dbc reads are
// wave-uniform (s_load). al[] pre-folds log2e so the hot loop is mul+v_exp per s.
// 256-thread blocks (grid 1024x2) pack the CUs finer than 512-thread blocks.
__global__ __launch_bounds__(256) void scan_k(
    const bf16* __restrict__ u, const bf16* __restrict__ sg,
    const float* __restrict__ dbc,
    const float* __restrict__ Wdt, const float* __restrict__ bdt,
    const float* __restrict__ Alog, const float* __restrict__ D,
    bf16* __restrict__ yg)
{
    const int n = blockIdx.x, e = blockIdx.y * 256 + threadIdx.x;
    float al[16], wdt[16], h[16];
#pragma unroll
    for (int s = 0; s < 16; s++) {
        al[s] = -__expf(Alog[e * 16 + s]) * 1.44269504f;   // * log2(e)
        h[s] = 0.f;
    }
#pragma unroll
    for (int k = 0; k < 16; k++) wdt[k] = Wdt[(size_t)k * EE + e];
    const float bdte = bdt[e], De = D[e];
    const float* __restrict__ rowp = dbc + (size_t)n * TT * 48;
    const size_t base = (size_t)n * TT * EE + e;
#pragma unroll 2
    for (int t = 0; t < TT; t++) {
        const float* __restrict__ r = rowp + t * 48;
        float a0 = bdte, a1 = 0.f, a2 = 0.f, a3 = 0.f;
#pragma unroll
        for (int k = 0; k < 4; k++) {
            a0 = fmaf(r[k],      wdt[k],      a0);
            a1 = fmaf(r[k + 4],  wdt[k + 4],  a1);
            a2 = fmaf(r[k + 8],  wdt[k + 8],  a2);
            a3 = fmaf(r[k + 12], wdt[k + 12], a3);
        }
        float acc = (a0 + a1) + (a2 + a3);
        float delta = (acc > 20.f)
            ? acc
            : 0.69314718056f * LOG2F(1.f + EXP2F(acc * 1.44269504f));
        size_t idx = base + (size_t)t * EE;
        float uv = toF(u[idx]);
        float du = delta * uv;
        float y0 = 0.f, y1 = 0.f, y2 = 0.f, y3 = 0.f;
#pragma unroll
        for (int s = 0; s < 16; s += 4) {
            float ad0 = EXP2F(delta * al[s]);
            float ad1 = EXP2F(delta * al[s + 1]);
            float ad2 = EXP2F(delta * al[s + 2]);
            float ad3 = EXP2F(delta * al[s + 3]);
            h[s]     = fmaf(ad0, h[s],     du * r[16 + s]);
            h[s + 1] = fmaf(ad1, h[s + 1], du * r[17 + s]);
            h[s + 2] = fmaf(ad2, h[s + 2], du * r[18 + s]);
            h[s + 3] = fmaf(ad3, h[s + 3], du * r[19 + s]);
            y0 = fmaf(r[32 + s], h[s],     y0);
            y1 = fmaf(r[33 + s], h[s + 1], y1);
            y2 = fmaf(r[34 + s], h[s + 2], y2);
            y3 = fmaf(r[35 + s], h[s + 3], y3);
        }
        float y = (y0 + y1) + (y2 + y3);
        yg[idx] = f2b((y + uv * De) * toF(sg[idx]));
    }
}

// ---------------- prep kernels ------------------------------------------------------
__global__ void cast_k(const float* __restrict__ in, bf16* __restrict__ out, int n) {
    int i = blockIdx.x * 256 + threadIdx.x;
    if (i < n) out[i] = f2b(in[i]);
}
__global__ void transT_k(const float* __restrict__ W, bf16* __restrict__ out, int K, int Nn) {
    int gid = blockIdx.x * 256 + threadIdx.x;
    if (gid >= K * Nn) return;
    int n = gid / K, k = gid - n * K;
    out[gid] = f2b(W[(size_t)k * Nn + n]);
}
__global__ void transmsgs_k(const float* __restrict__ msgs, bf16* __restrict__ msgsT) {
    int gid = blockIdx.x * 256 + threadIdx.x;
    int c = gid >> 10, j = gid & 1023;
    msgsT[gid] = f2b(msgs[(size_t)j * 256 + c]);
}
__global__ void wdbct_k(const float* __restrict__ Wd, const float* __restrict__ WB,
                        const float* __restrict__ WC, bf16* __restrict__ out,
                        const float* __restrict__ bd, const float* __restrict__ bB,
                        const float* __restrict__ bC, float* __restrict__ biascat) {
    int gid = blockIdx.x * 256 + threadIdx.x;
    if (gid < 48) biascat[gid] = (gid < 16) ? bd[gid] : (gid < 32) ? bB[gid - 16] : bC[gid - 32];
    if (gid >= 64 * 512) return;
    int n = gid >> 9, k = gid & 511;
    float v = 0.f;
    if (n < 16)      v = Wd[(size_t)k * 16 + n];
    else if (n < 32) v = WB[(size_t)k * 16 + (n - 16)];
    else if (n < 48) v = WC[(size_t)k * 16 + (n - 32)];
    out[gid] = f2b(v);
}

extern "C" void kernel_launch(void* const* d_in, const int* in_sizes, int n_in,
                              void* d_out, int out_size, void* d_ws, size_t ws_size,
                              hipStream_t stream)
{
    const float* adj   = (const float*)d_in[0];
    const float* pos   = (const float*)d_in[1];
    const float* g1Wm  = (const float*)d_in[2];
    const float* g1bm  = (const float*)d_in[3];
    const float* g1Wq  = (const float*)d_in[4];
    const float* g1Wk  = (const float*)d_in[5];
    const float* g1gb  = (const float*)d_in[6];
    const float* g1Wu  = (const float*)d_in[7];
    const float* g1bu  = (const float*)d_in[8];
    const float* g1lg  = (const float*)d_in[9];
    const float* g1lb  = (const float*)d_in[10];
    const float* g2Wm  = (const float*)d_in[11];
    const float* g2bm  = (const float*)d_in[12];
    const float* g2Wu  = (const float*)d_in[13];
    const float* g2bu  = (const float*)d_in[14];
    const float* g2lg  = (const float*)d_in[15];
    const float* g2lb  = (const float*)d_in[16];
    const float* mlg   = (const float*)d_in[17];
    const float* mlb   = (const float*)d_in[18];
    const float* mWin  = (const float*)d_in[19];
    const float* mbin  = (const float*)d_in[20];
    const float* mWd   = (const float*)d_in[21];
    const float* mbd   = (const float*)d_in[22];
    const float* mWdt  = (const float*)d_in[23];
    const float* mbdt  = (const float*)d_in[24];
    const float* mWB   = (const float*)d_in[25];
    const float* mbB   = (const float*)d_in[26];
    const float* mWC   = (const float*)d_in[27];
    const float* mbC   = (const float*)d_in[28];
    const float* mAlog = (const float*)d_in[29];
    const float* mD    = (const float*)d_in[30];
    const float* mWout = (const float*)d_in[31];
    const float* mbout = (const float*)d_in[32];
    float* out = (float*)d_out;
    char* ws = (char*)d_ws;

    const size_t BIGE = (size_t)TT * NN_ * 256;
    size_t o = 0;
    auto alloc = [&](size_t bytes) { size_t r = o; o += (bytes + 255) & ~(size_t)255; return r; };

    float* msgs  = (float*)(ws + alloc((size_t)NN_ * 256 * 4));
    float* q     = (float*)(ws + alloc((size_t)NN_ * 256 * 4));
    float* kk    = (float*)(ws + alloc((size_t)NN_ * 256 * 4));
    bf16*  gatesb = (bf16*)(ws + alloc((size_t)NN_ * NN_ * 2));
    unsigned long long* adjbits =
        (unsigned long long*)(ws + alloc((size_t)TT * NN_ * NN_ / 8));
    bf16*  Ra    = (bf16*)(ws + alloc(BIGE * 2));                 // agg / xn
    size_t off_x1 = alloc(BIGE * 2);
    bf16*  x1    = (bf16*)(ws + off_x1);
    bf16*  agg2  = (bf16*)(ws + alloc(BIGE * 2));                 // contiguous after x1
    bf16*  x2    = (bf16*)(ws + alloc(BIGE * 2));                 // res, [N,T,H]
    bf16*  yg    = (bf16*)(ws + alloc(BIGE * 2));
    bf16*  sg    = (bf16*)(ws + alloc((size_t)NN_ * TT * EE * 2));
    float* dbc   = (float*)(ws + alloc((size_t)TT * NN_ * 48 * 4));  // [M,48] d1|Bm|Cm
    bf16*  u     = (bf16*)(ws + off_x1);                          // aliases x1+agg2
    // transposed bf16 weights / staging
    bf16* posb   = (bf16*)(ws + alloc((size_t)NN_ * 256 * 2));
    bf16* g1WuT  = (bf16*)(ws + alloc((size_t)256 * 512 * 2));
    bf16* g2WmT  = (bf16*)(ws + alloc((size_t)256 * 256 * 2));
    bf16* g2WuT  = (bf16*)(ws + alloc((size_t)256 * 512 * 2));
    bf16* mWinT  = (bf16*)(ws + alloc((size_t)1024 * 256 * 2));
    bf16* mWoutT = (bf16*)(ws + alloc((size_t)256 * 512 * 2));
    bf16* WdBCT  = (bf16*)(ws + alloc((size_t)64 * 512 * 2));
    float* biascat = (float*)(ws + alloc(64 * 4));
    bf16* msgsT  = (bf16*)(ws + alloc((size_t)256 * 1024 * 2));
    bf16* msgs2T = (bf16*)(ws + alloc(BIGE * 2));

    const unsigned ALLR = 0xFFFFFFFFu;
    const int M = TT * NN_;

    // prep
    packadj_k<<<2048, 256, 0, stream>>>((const float4*)adj, (unsigned int*)adjbits);
    cast_k<<<NN_, 256, 0, stream>>>(pos, posb, NN_ * 256);
    transT_k<<<(512 * 256 + 255) / 256, 256, 0, stream>>>(g1Wu, g1WuT, 512, 256);
    transT_k<<<(256 * 256 + 255) / 256, 256, 0, stream>>>(g2Wm, g2WmT, 256, 256);
    transT_k<<<(512 * 256 + 255) / 256, 256, 0, stream>>>(g2Wu, g2WuT, 512, 256);
    transT_k<<<(256 * 1024 + 255) / 256, 256, 0, stream>>>(mWin, mWinT, 256, 1024);
    transT_k<<<(512 * 256 + 255) / 256, 256, 0, stream>>>(mWout, mWoutT, 512, 256);
    wdbct_k<<<(64 * 512 + 255) / 256, 256, 0, stream>>>(mWd, mWB, mWC, WdBCT, mbd, mbB, mbC, biascat);

    // S0: msgs = pos @ g1_Wm + bm (f32)
    gemm_k<false, EPI_F32><<<dim3(16, 4), 256, 0, stream>>>(
        pos, g1Wm, msgs, g1bm, nullptr, 1.f, NN_, 256, 256, 256, 256);
    transmsgs_k<<<1024, 256, 0, stream>>>(msgs, msgsT);
    // S1: q, k
    gemm_k<false, EPI_F32><<<dim3(16, 4), 256, 0, stream>>>(
        msgs, g1Wq, q, nullptr, nullptr, 1.f, NN_, 256, 256, 256, 256);
    gemm_k<false, EPI_F32><<<dim3(16, 4), 256, 0, stream>>>(
        msgs, g1Wk, kk, nullptr, nullptr, 1.f, NN_, 256, 256, 256, 256);
    // S2: gates = sigmoid(q @ k^T / 16 + gb) -> bf16 (exact wrt old f2b(adj*gate))
    gemm_k<true, EPI_SIG_B16><<<dim3(16, 16), 256, 0, stream>>>(
        q, kk, (float*)gatesb, nullptr, g1gb, 1.f / 16.f, NN_, NN_, 256, 256, 256);
    // S3: agg -> Ra
    aggmm_k<true><<<512, 256, 0, stream>>>(
        (const unsigned char*)adjbits, gatesb, msgsT, Ra);
    // S4(+S5): x1 = LN(relu(cat(posb,Ra) @ Wu1 + bu1))
    mfma_k<64, 256, true, E_LN1><<<dim3(1024, 1), 256, 0, stream>>>(
        posb, Ra, 1023u, g1WuT, g1bu, nullptr, x1, nullptr,
        g1lg, g1lb, nullptr, nullptr, nullptr, M, 512);
    // S6: msgs2 = x1 @ Wm2 + bm2 -> msgs2T ([t][c][j])
    mfma_k<64, 256, false, E_BF16T><<<dim3(1024, 1), 256, 0, stream>>>(
        x1, x1, ALLR, g2WmT, g2bm, nullptr, msgs2T, nullptr,
        nullptr, nullptr, nullptr, nullptr, nullptr, M, 256);
    // S7: agg2 = adj @ msgs2
    aggmm_k<false><<<512, 256, 0, stream>>>(
        (const unsigned char*)adjbits, nullptr, msgs2T, agg2);
    // S8(+S9+S10): x2 = LN(relu(cat(x1,agg2)@Wu2+bu2)) [N,T,H], xn = LN2 -> Ra [N,T,H]
    mfma_k<64, 256, true, E_LN2><<<dim3(1024, 1), 256, 0, stream>>>(
        x1, agg2, ALLR, g2WuT, g2bu, nullptr, x2, Ra,
        g2lg, g2lb, mlg, mlb, nullptr, M, 512);
    // S11: u/sg = silu halves of xn @ Win + bin
    mfma_k<64, 256, false, E_SILU><<<dim3(1024, 4), 256, 0, stream>>>(
        Ra, Ra, ALLR, mWinT, mbin, nullptr, u, sg,
        nullptr, nullptr, nullptr, nullptr, nullptr, M, 256);
    // S12 fused: dbc = u @ [Wd|WB|WC] + biases  ([M,48] interleaved)
    mfma_k<256, 64, false, E_TRI><<<dim3(256, 1), 256, 0, stream>>>(
        u, u, ALLR, WdBCT, biascat, dbc, nullptr, nullptr,
        nullptr, nullptr, nullptr, nullptr, nullptr, M, 512);
    // S13: selective scan -> yg  (block per (n, e-half))
    scan_k<<<dim3(NN_, 2), 256, 0, stream>>>(u, sg, dbc, mWdt, mbdt, mAlog, mD, yg);
    // S14: out = yg @ Wout + bout + res -> [T,N,H] f32
    mfma_k<64, 256, false, E_OUT><<<dim3(1024, 1), 256, 0, stream>>>(
        yg, yg, ALLR, mWoutT, mbout, out, nullptr, nullptr,
        nullptr, nullptr, nullptr, nullptr, x2, M, 512);

    (void)in_sizes; (void)n_in; (void)out_size; (void)ws_size;
}